// Round 1
// baseline (306.064 us; speedup 1.0000x reference)
//
#include <hip/hip_runtime.h>
#include <hip/hip_bf16.h>
#include <math.h>

#define V_N 4096
#define E_N 2048
#define F_N 512
#define H_N 256

typedef unsigned short u16;
typedef __attribute__((ext_vector_type(8))) short short8;
typedef __attribute__((ext_vector_type(4))) float f32x4;

__device__ __forceinline__ float bf2f(u16 u) {
  union { float f; unsigned int q; } x; x.q = ((unsigned int)u) << 16; return x.f;
}
__device__ __forceinline__ u16 f2bf(float f) {
  union { float f; unsigned int q; } x; x.f = f;
  unsigned int q = x.q + 0x7FFFu + ((x.q >> 16) & 1u);
  return (u16)(q >> 16);
}

__device__ __forceinline__ void gload_lds16(const u16* g, u16* l) {
  __builtin_amdgcn_global_load_lds((const __attribute__((address_space(1))) void*)g,
                                   (__attribute__((address_space(3))) void*)l,
                                   16, 0, 0);
}

// ---------------- MFMA NT GEMM: C[m,n] = sum_k A[m,k]*B[n,k] ----------------
// A: (M,K) row-major bf16, B: (N,K) row-major bf16. 128x128 tile, BK=64,
// 256 threads (4 waves, 2x2 wave grid, 4x4 16x16x32 fragments per wave).
#define BM 128
#define BN 128
#define BK 64

// EPI: 0 = f32 store (atomicAdd when ksplit>1)
//      1 = bf16 store * scale
//      2 = H-matrix: bf16( exp(-(colv[col]+rowv[row]-2*acc+bias)*scF[1]) )
//      3 = blend:    f32( (1-scF[0])*G + scF[0]*rsqrt(DV[r])*rsqrt(DV[c])*acc )
template<int EPI>
__global__ __launch_bounds__(256)
void gemm_nt(const u16* __restrict__ A, const u16* __restrict__ B,
             int M, int N, int K, int ksplit, float scale,
             float* __restrict__ outF, u16* __restrict__ outB,
             const float* __restrict__ rowv, const float* __restrict__ colv,
             const float* __restrict__ scF, const float* __restrict__ biasp,
             const float* __restrict__ Gin, const float* __restrict__ DVv)
{
  __shared__ __align__(16) u16 As[BM * BK];
  __shared__ __align__(16) u16 Bs[BN * BK];
  const int tid  = threadIdx.x;
  const int lane = tid & 63;
  const int wave = tid >> 6;
  const int wr = wave >> 1, wc = wave & 1;
  const int tileM = blockIdx.y * BM;
  const int tileN = blockIdx.x * BN;
  const int kper = K / ksplit;
  const int kbeg = blockIdx.z * kper;
  const int kend = kbeg + kper;

  const int srow = wave * 8 + (lane >> 3);   // staging row within 32-row round
  const int scol = (lane & 7) * 8;           // staging k-offset (ushorts)

  f32x4 acc[4][4] = {};

  const u16* Arow = A + (size_t)tileM * K;
  const u16* Brow = B + (size_t)tileN * K;

  for (int kt = kbeg; kt < kend; kt += BK) {
    __syncthreads();
#pragma unroll
    for (int r = 0; r < 4; ++r) {
      int row = r * 32 + srow;
      gload_lds16(Arow + (size_t)row * K + kt + scol, &As[row * BK + scol]);
      gload_lds16(Brow + (size_t)row * K + kt + scol, &Bs[row * BK + scol]);
    }
    __syncthreads();
#pragma unroll
    for (int ks = 0; ks < 2; ++ks) {
      short8 af[4], bfr[4];
#pragma unroll
      for (int m = 0; m < 4; ++m)
        af[m] = *(const short8*)&As[(wr * 64 + m * 16 + (lane & 15)) * BK + ks * 32 + (lane >> 4) * 8];
#pragma unroll
      for (int n = 0; n < 4; ++n)
        bfr[n] = *(const short8*)&Bs[(wc * 64 + n * 16 + (lane & 15)) * BK + ks * 32 + (lane >> 4) * 8];
#pragma unroll
      for (int m = 0; m < 4; ++m)
#pragma unroll
        for (int n = 0; n < 4; ++n)
          acc[m][n] = __builtin_amdgcn_mfma_f32_16x16x32_bf16(af[m], bfr[n], acc[m][n], 0, 0, 0);
    }
  }

  const int r0 = tileM + wr * 64 + ((lane >> 4) << 2);
  const int c0 = tileN + wc * 64 + (lane & 15);
  float theta = 0.f, inv2s2 = 0.f, bias = 0.f;
  if constexpr (EPI == 2) { inv2s2 = scF[1]; bias = biasp[0]; }
  if constexpr (EPI == 3) { theta = scF[0]; }
#pragma unroll
  for (int m = 0; m < 4; ++m) {
#pragma unroll
    for (int j = 0; j < 4; ++j) {
      const int row = r0 + m * 16 + j;
      float rsr = 0.f, cr = 0.f;
      if constexpr (EPI == 3) rsr = rsqrtf(DVv[row]);
      if constexpr (EPI == 2) cr = rowv[row];
#pragma unroll
      for (int n = 0; n < 4; ++n) {
        const int col = c0 + n * 16;
        const size_t idx = (size_t)row * N + col;
        const float v = acc[m][n][j];
        if constexpr (EPI == 0) {
          if (ksplit == 1) outF[idx] = v; else atomicAdd(&outF[idx], v);
        } else if constexpr (EPI == 1) {
          outB[idx] = f2bf(v * scale);
        } else if constexpr (EPI == 2) {
          float dist = colv[col] + cr - 2.f * v + bias;
          outB[idx] = f2bf(__expf(-dist * inv2s2));
        } else {
          float gv = Gin[idx];
          outF[idx] = (1.f - theta) * gv + theta * rsr * rsqrtf(DVv[col]) * v;
        }
      }
    }
  }
}

// ---------------- utility kernels ----------------

__global__ void k_scalars(const int* num, const int* sigma, float* scF) {
  if (threadIdx.x == 0 && blockIdx.x == 0) {
    float n = (float)num[0];
    scF[0] = 1.f - (1.f - 0.01f) * (cosf(3.14159265358979f * (n - 1.f) / 10.f) + 1.f) * 0.5f;
    float s = (float)sigma[0];
    scF[1] = 1.f / (2.f * s * s);
  }
}

__global__ void k_deg(const float* __restrict__ adj, float* __restrict__ deg) {
  int e = blockIdx.x * 256 + threadIdx.x;
  int v0 = blockIdx.y * 128;
  float s = 0.f;
  for (int v = v0; v < v0 + 128; ++v) s += adj[(size_t)v * E_N + e];
  atomicAdd(&deg[e], s);
}

__global__ void k_convf(const float* __restrict__ in, u16* __restrict__ out, int n4) {
  int i = blockIdx.x * 256 + threadIdx.x;
  if (i >= n4) return;
  float4 v = ((const float4*)in)[i];
  ushort4 o; o.x = f2bf(v.x); o.y = f2bf(v.y); o.z = f2bf(v.z); o.w = f2bf(v.w);
  ((ushort4*)out)[i] = o;
}

__global__ void k_convW(const float* __restrict__ Wl, const float* __restrict__ Wv,
                        u16* __restrict__ WT) {
  int id = blockIdx.x * 256 + threadIdx.x;   // 512*512 outputs, row n, col k
  int n = id >> 9, k = id & 511;
  float v = (n < 256) ? Wl[(size_t)k * 256 + n] : Wv[(size_t)k * 256 + (n - 256)];
  WT[id] = f2bf(v);
}

__global__ void k_adjT(const float* __restrict__ adj, u16* __restrict__ adjT) {
  __shared__ float t[32][33];
  int e0 = blockIdx.x * 32, v0 = blockIdx.y * 32;
  int tx = threadIdx.x & 31, ty = threadIdx.x >> 5;   // 32x8
  for (int i = ty; i < 32; i += 8)
    t[i][tx] = adj[(size_t)(v0 + i) * E_N + e0 + tx];
  __syncthreads();
  for (int i = ty; i < 32; i += 8)
    adjT[(size_t)(e0 + i) * V_N + v0 + tx] = f2bf(t[tx][i]);
}

// fwcat (V,512) -> fwlinT (256,V) bf16 [cols 0..255 transposed],
//                  fvb (V,256) bf16 + fvT (256,V) bf16 [cols 256..511]
__global__ void k_splitfw(const float* __restrict__ fw, u16* __restrict__ fwlinT,
                          u16* __restrict__ fvb, u16* __restrict__ fvT) {
  __shared__ float t[32][33];
  int h0 = blockIdx.x * 32, v0 = blockIdx.y * 32;
  int tx = threadIdx.x & 31, ty = threadIdx.x >> 5;
  for (int i = ty; i < 32; i += 8) {
    float val = fw[(size_t)(v0 + i) * 512 + h0 + tx];
    t[i][tx] = val;
    if (h0 >= 256) fvb[(size_t)(v0 + i) * 256 + (h0 - 256) + tx] = f2bf(val);
  }
  __syncthreads();
  u16* oT = (h0 < 256) ? fwlinT : fvT;
  int hb = (h0 < 256) ? h0 : h0 - 256;
  for (int i = ty; i < 32; i += 8)
    oT[(size_t)(hb + i) * V_N + v0 + tx] = f2bf(t[tx][i]);
}

// LayerNorm over rows of 256. mode mulw=1: outB = bf16(xln*w) (for sw); else bf16(xln).
// outA[row] = sum_h w[h]*xln^2.
__global__ void k_ln(const float* __restrict__ X, const float* __restrict__ divv,
                     const float* __restrict__ g, const float* __restrict__ b,
                     const float* __restrict__ w, u16* __restrict__ outB,
                     float* __restrict__ outA, int mulw)
{
  __shared__ float sm[8];
  int row = blockIdx.x, tid = threadIdx.x, lane = tid & 63, wave = tid >> 6;
  float x = X[(size_t)row * 256 + tid];
  if (divv) x /= divv[row];
  float s1 = x, s2 = x * x;
#pragma unroll
  for (int o = 32; o > 0; o >>= 1) { s1 += __shfl_down(s1, o); s2 += __shfl_down(s2, o); }
  if (lane == 0) { sm[wave] = s1; sm[4 + wave] = s2; }
  __syncthreads();
  float sx  = sm[0] + sm[1] + sm[2] + sm[3];
  float sx2 = sm[4] + sm[5] + sm[6] + sm[7];
  float mu  = sx * (1.f / 256.f);
  float var = sx2 * (1.f / 256.f) - mu * mu;
  float rs  = rsqrtf(var + 1e-5f);
  float xln = (x - mu) * rs * g[tid] + b[tid];
  outB[(size_t)row * 256 + tid] = f2bf(mulw ? xln * w[tid] : xln);
  float t = w[tid] * xln * xln;
  __syncthreads();
#pragma unroll
  for (int o = 32; o > 0; o >>= 1) t += __shfl_down(t, o);
  if (lane == 0) sm[wave] = t;
  __syncthreads();
  if (tid == 0) outA[row] = sm[0] + sm[1] + sm[2] + sm[3];
}

__global__ void k_softmax(u16* __restrict__ S) {  // in-place rows of 4096, bf16
  __shared__ float sm[8];
  size_t base = (size_t)blockIdx.x * 4096;
  int tid = threadIdx.x, lane = tid & 63, wave = tid >> 6;
  short8* p = (short8*)(S + base);
  short8 r0 = p[2 * tid], r1 = p[2 * tid + 1];
  float v[16];
#pragma unroll
  for (int i = 0; i < 8; ++i) { v[i] = bf2f((u16)r0[i]); v[8 + i] = bf2f((u16)r1[i]); }
  float mx = v[0];
#pragma unroll
  for (int i = 1; i < 16; ++i) mx = fmaxf(mx, v[i]);
#pragma unroll
  for (int o = 32; o > 0; o >>= 1) mx = fmaxf(mx, __shfl_down(mx, o));
  if (lane == 0) sm[wave] = mx;
  __syncthreads();
  mx = fmaxf(fmaxf(sm[0], sm[1]), fmaxf(sm[2], sm[3]));
  float se = 0.f;
#pragma unroll
  for (int i = 0; i < 16; ++i) { v[i] = __expf(v[i] - mx); se += v[i]; }
  __syncthreads();
#pragma unroll
  for (int o = 32; o > 0; o >>= 1) se += __shfl_down(se, o);
  if (lane == 0) sm[4 + wave] = se;
  __syncthreads();
  se = sm[4] + sm[5] + sm[6] + sm[7];
  float inv = 1.f / se;
#pragma unroll
  for (int i = 0; i < 8; ++i) { r0[i] = (short)f2bf(v[i] * inv); r1[i] = (short)f2bf(v[8 + i] * inv); }
  p[2 * tid] = r0; p[2 * tid + 1] = r1;
}

__global__ void k_rowsum(const u16* __restrict__ Hm, float* __restrict__ DV) {
  __shared__ float sm[4];
  int row = blockIdx.x, tid = threadIdx.x, lane = tid & 63, wave = tid >> 6;
  const short8* p = (const short8*)(Hm + (size_t)row * 2048);
  short8 r = p[tid];
  float s = 0.f;
#pragma unroll
  for (int i = 0; i < 8; ++i) s += bf2f((u16)r[i]);
#pragma unroll
  for (int o = 32; o > 0; o >>= 1) s += __shfl_down(s, o);
  if (lane == 0) sm[wave] = s;
  __syncthreads();
  if (tid == 0) DV[row] = sm[0] + sm[1] + sm[2] + sm[3];
}

__global__ void k_colsum(const u16* __restrict__ Hm, float* __restrict__ DE) {
  int e = blockIdx.x * 256 + threadIdx.x;
  int v0 = blockIdx.y * 128;
  float s = 0.f;
  for (int v = v0; v < v0 + 128; ++v) s += bf2f(Hm[(size_t)v * 2048 + e]);
  atomicAdd(&DE[e], s);
}

__global__ void k_makeHd(u16* __restrict__ Hm, const float* __restrict__ DE) {
  int id = blockIdx.x * 256 + threadIdx.x;   // 1M chunks of 8
  int c = id & 255, row = id >> 8;
  short8* p = (short8*)(Hm + (size_t)row * 2048);
  short8 r = p[c];
  const float4* dp = (const float4*)(DE + c * 8);
  float4 d0 = dp[0], d1 = dp[1];
  float sc[8] = { rsqrtf(d0.x), rsqrtf(d0.y), rsqrtf(d0.z), rsqrtf(d0.w),
                  rsqrtf(d1.x), rsqrtf(d1.y), rsqrtf(d1.z), rsqrtf(d1.w) };
#pragma unroll
  for (int i = 0; i < 8; ++i) r[i] = (short)f2bf(bf2f((u16)r[i]) * sc[i]);
  p[c] = r;
}

// ---------------- host ----------------

extern "C" void kernel_launch(void* const* d_in, const int* in_sizes, int n_in,
                              void* d_out, int out_size, void* d_ws, size_t ws_size,
                              hipStream_t stream)
{
  const float* adj   = (const float*)d_in[0];
  const float* G     = (const float*)d_in[1];
  const float* feats = (const float*)d_in[2];
  const float* Wl    = (const float*)d_in[3];
  const float* Wv    = (const float*)d_in[4];
  const float* wo_w  = (const float*)d_in[5];
  const float* wo_b  = (const float*)d_in[6];
  const float* g1    = (const float*)d_in[7];
  const float* b1    = (const float*)d_in[8];
  const float* g2    = (const float*)d_in[9];
  const float* b2    = (const float*)d_in[10];
  const int*   num   = (const int*)d_in[11];
  const int*   sigma = (const int*)d_in[12];
  float* out = (float*)d_out;

  char* w = (char*)d_ws;
  auto take = [&](size_t b) { void* p = (void*)w; w += (b + 255) & ~(size_t)255; return p; };
  float* scF   = (float*)take(256);
  float* deg   = (float*)take(E_N * 4);
  float* DV    = (float*)take(V_N * 4);
  float* DE    = (float*)take(E_N * 4);
  float* aE    = (float*)take(E_N * 4);
  float* cV    = (float*)take(V_N * 4);
  // big region 0: featsb + WcatT + adjTb; reused for Hb after G2
  char* big0   = (char*)take((size_t)V_N * F_N * 2 + 512 * 512 * 2 + (size_t)E_N * V_N * 2);
  u16* featsb  = (u16*)big0;
  u16* WcatT   = (u16*)(big0 + (size_t)V_N * F_N * 2);
  u16* adjTb   = (u16*)(big0 + (size_t)V_N * F_N * 2 + 512 * 512 * 2);
  u16* Hb      = (u16*)big0;                         // alias, live after adjTb dead
  // big region 1: fwcat (8MB); reused for d_mat (4MB) + db (2MB)
  char* big1   = (char*)take((size_t)V_N * 512 * 4);
  float* fwcat = (float*)big1;
  float* d_mat = (float*)big1;                       // alias, live after fwcat dead
  u16* db      = (u16*)(big1 + (size_t)V_N * H_N * 4);
  u16* fwlinT  = (u16*)take((size_t)H_N * V_N * 2);
  u16* fvb     = (u16*)take((size_t)V_N * H_N * 2);
  u16* fvT     = (u16*)take((size_t)H_N * V_N * 2);
  float* s_raw = (float*)take((size_t)E_N * H_N * 4);
  u16* swb     = (u16*)take((size_t)E_N * H_N * 2);
  u16* scoresb = (u16*)take((size_t)V_N * V_N * 2);
  (void)in_sizes; (void)n_in; (void)out_size;
  if ((size_t)(w - (char*)d_ws) > ws_size) return;   // ws too small: bail

  hipMemsetAsync(deg, 0, E_N * 4, stream);
  hipMemsetAsync(DE, 0, E_N * 4, stream);
  hipMemsetAsync(s_raw, 0, (size_t)E_N * H_N * 4, stream);

  k_scalars<<<1, 64, 0, stream>>>(num, sigma, scF);
  k_deg<<<dim3(E_N / 256, 32), 256, 0, stream>>>(adj, deg);
  k_convf<<<(V_N * F_N / 4) / 256, 256, 0, stream>>>(feats, featsb, V_N * F_N / 4);
  k_convW<<<(512 * 512) / 256, 256, 0, stream>>>(Wl, Wv, WcatT);
  k_adjT<<<dim3(E_N / 32, V_N / 32), 256, 0, stream>>>(adj, adjTb);

  // G1: fwcat = feats @ [W_lin|W_v]   (M=V, N=512, K=512)
  gemm_nt<0><<<dim3(512 / BN, V_N / BM), 256, 0, stream>>>(
      featsb, WcatT, V_N, 512, 512, 1, 0.f,
      fwcat, nullptr, nullptr, nullptr, nullptr, nullptr, nullptr, nullptr);
  k_splitfw<<<dim3(16, V_N / 32), 256, 0, stream>>>(fwcat, fwlinT, fvb, fvT);

  // G2: s_raw = adj.T @ fwlin   (M=E, N=H, K=V, split-K 8)
  gemm_nt<0><<<dim3(H_N / BN, E_N / BM, 8), 256, 0, stream>>>(
      adjTb, fwlinT, E_N, H_N, V_N, 8, 0.f,
      s_raw, nullptr, nullptr, nullptr, nullptr, nullptr, nullptr, nullptr);
  k_ln<<<E_N, 256, 0, stream>>>(s_raw, deg, g1, b1, wo_w, swb, aE, 1);

  // G3: scores = fv @ fv.T / 16   (bf16 out)
  gemm_nt<1><<<dim3(V_N / BN, V_N / BM), 256, 0, stream>>>(
      fvb, fvb, V_N, V_N, H_N, 1, 0.0625f,
      nullptr, scoresb, nullptr, nullptr, nullptr, nullptr, nullptr, nullptr);
  k_softmax<<<V_N, 256, 0, stream>>>(scoresb);

  hipMemsetAsync(d_mat, 0, (size_t)V_N * H_N * 4, stream);
  // G4: d = attn @ fv   (M=V, N=H, K=V, split-K 8)
  gemm_nt<0><<<dim3(H_N / BN, V_N / BM, 8), 256, 0, stream>>>(
      scoresb, fvT, V_N, H_N, V_N, 8, 0.f,
      d_mat, nullptr, nullptr, nullptr, nullptr, nullptr, nullptr, nullptr);
  k_ln<<<V_N, 256, 0, stream>>>(d_mat, nullptr, g2, b2, wo_w, db, cV, 0);

  // G5: Hb[v,e] = exp(-(a[e]+c[v]-2*(d.sw)+b)/(2*sigma^2))   (M=V, N=E, K=H)
  gemm_nt<2><<<dim3(E_N / BN, V_N / BM), 256, 0, stream>>>(
      db, swb, V_N, E_N, H_N, 1, 0.f,
      nullptr, Hb, cV, aE, scF, wo_b, nullptr, nullptr);

  k_rowsum<<<V_N, 256, 0, stream>>>(Hb, DV);
  k_colsum<<<dim3(E_N / 256, 32), 256, 0, stream>>>(Hb, DE);
  k_makeHd<<<V_N, 256, 0, stream>>>(Hb, DE);

  // G6: out = (1-theta)*G + theta*invDV_i*invDV_j*(Hd @ Hd.T)   (M=N=V, K=E)
  gemm_nt<3><<<dim3(V_N / BN, V_N / BM), 256, 0, stream>>>(
      Hb, Hb, V_N, V_N, E_N, 1, 0.f,
      out, nullptr, nullptr, nullptr, scF, nullptr, G, DV);
}

// Round 2
// 269.401 us; speedup vs baseline: 1.1361x; 1.1361x over previous
//
#include <hip/hip_runtime.h>
#include <hip/hip_bf16.h>
#include <math.h>

#define V_N 4096
#define E_N 2048
#define F_N 512
#define H_N 256

typedef unsigned short u16;
typedef __attribute__((ext_vector_type(8))) short short8;
typedef __attribute__((ext_vector_type(4))) float f32x4;

__device__ __forceinline__ float bf2f(u16 u) {
  union { float f; unsigned int q; } x; x.q = ((unsigned int)u) << 16; return x.f;
}
__device__ __forceinline__ u16 f2bf(float f) {
  union { float f; unsigned int q; } x; x.f = f;
  unsigned int q = x.q + 0x7FFFu + ((x.q >> 16) & 1u);
  return (u16)(q >> 16);
}

__device__ __forceinline__ void gload_lds16(const u16* g, u16* l) {
  __builtin_amdgcn_global_load_lds((const __attribute__((address_space(1))) void*)g,
                                   (__attribute__((address_space(3))) void*)l,
                                   16, 0, 0);
}

// =================== 256x256 8-phase MFMA NT GEMM (T1+T2+T3+T4+T5) ===========
// C[m,n] = sum_k A[m,k]*B[n,k]. A:(M,K), B:(N,K) row-major bf16.
// 512 threads = 8 waves (2 Mwaves x 4 Nwaves), wave tile 128x64, BK=64.
// LDS: 2 buffers x (A 256x64 + B 256x64) bf16 = 128 KiB (dynamic, opt-in).
// XOR swizzle: 16B chunk c of row r stored at c^(r&7); applied on the
// global SOURCE of global_load_lds (dest linear) and on ds_read addresses.

#define BARX do { asm volatile("" ::: "memory"); __builtin_amdgcn_s_barrier(); \
                  asm volatile("" ::: "memory"); } while (0)

#define LDA_Q(buf, mh_) do { \
  _Pragma("unroll") \
  for (int m_ = 0; m_ < 4; ++m_) { \
    _Pragma("unroll") \
    for (int ks_ = 0; ks_ < 2; ++ks_) { \
      int R_ = wr * 128 + (mh_) * 64 + m_ * 16 + (lane & 15); \
      int c_ = (ks_ * 4 + (lane >> 4)) ^ (R_ & 7); \
      afr[m_ * 2 + ks_] = *(const short8*)((buf) + R_ * 64 + c_ * 8); \
    } } \
} while (0)

#define LDB_Q(buf, nh_) do { \
  _Pragma("unroll") \
  for (int n_ = 0; n_ < 2; ++n_) { \
    _Pragma("unroll") \
    for (int ks_ = 0; ks_ < 2; ++ks_) { \
      int R_ = wc * 64 + (nh_) * 32 + n_ * 16 + (lane & 15); \
      int c_ = (ks_ * 4 + (lane >> 4)) ^ (R_ & 7); \
      bfr[(nh_) * 4 + n_ * 2 + ks_] = *(const short8*)((buf) + R_ * 64 + c_ * 8); \
    } } \
} while (0)

#define MMA_Q(mh_, nh_) do { \
  __builtin_amdgcn_s_setprio(1); \
  _Pragma("unroll") \
  for (int m_ = 0; m_ < 4; ++m_) { \
    _Pragma("unroll") \
    for (int n_ = 0; n_ < 2; ++n_) { \
      _Pragma("unroll") \
      for (int ks_ = 0; ks_ < 2; ++ks_) \
        acc[(mh_) * 4 + m_][(nh_) * 2 + n_] = __builtin_amdgcn_mfma_f32_16x16x32_bf16( \
            afr[m_ * 2 + ks_], bfr[(nh_) * 4 + n_ * 2 + ks_], \
            acc[(mh_) * 4 + m_][(nh_) * 2 + n_], 0, 0, 0); \
    } } \
  __builtin_amdgcn_s_setprio(0); \
} while (0)

// Stage one half-tile (128 rows) of a 256-row LDS tile. BAND=64 for A
// (halves = {0-63,128-191} / {64-127,192-255}), BAND=32 for B (32-row bands).
// Each thread issues 2 x 16B global_load_lds; LDS dest linear, source XOR'd.
template<int BAND>
__device__ __forceinline__ void stage_half(const u16* __restrict__ g, int K, int kt,
                                           u16* lds, int wave, int lane, int h) {
#pragma unroll
  for (int l = 0; l < 2; ++l) {
    int rl = wave * 16 + l * 8;                       // 8-row block start, 0..120
    int R0 = (rl & (BAND - 1)) + (rl & ~(BAND - 1)) * 2 + h * BAND;
    int r  = R0 + (lane >> 3);
    int c  = (lane & 7) ^ (r & 7);
    gload_lds16(g + (size_t)r * K + kt + c * 8, lds + R0 * 64 + lane * 8);
  }
}

// EPI: 1 = bf16 store * scale
//      2 = H-matrix: bf16( exp(-(colv[col]+rowv[row]-2*acc+bias)*scF[1]) )
//      3 = blend:    f32( (1-scF[0])*G + scF[0]*rsqrt(DV[r])*rsqrt(DV[c])*acc )
template<int EPI>
__global__ __launch_bounds__(512, 2)
void gemm_nt_big(const u16* __restrict__ A, const u16* __restrict__ B,
                 int M, int N, int K, float scale,
                 float* __restrict__ outF, u16* __restrict__ outB,
                 const float* __restrict__ rowv, const float* __restrict__ colv,
                 const float* __restrict__ scF, const float* __restrict__ biasp,
                 const float* __restrict__ Gin, const float* __restrict__ DVv)
{
  extern __shared__ __align__(16) u16 lds[];
  u16* As0 = lds;
  u16* Bs0 = lds + 256 * 64;
  u16* As1 = lds + 2 * 256 * 64;
  u16* Bs1 = lds + 3 * 256 * 64;

  const int tid = threadIdx.x, lane = tid & 63, wave = tid >> 6;
  const int wr = wave >> 2, wc = wave & 3;

  // XCD-aware swizzle (bijective: nwg % 8 == 0 for all our launches)
  const int nwg = gridDim.x * gridDim.y;
  const int lin = blockIdx.y * gridDim.x + blockIdx.x;
  const int swz = (lin & 7) * (nwg >> 3) + (lin >> 3);
  const int bx = swz % gridDim.x, by = swz / gridDim.x;
  const int tileM = by * 256, tileN = bx * 256;

  const u16* Ag = A + (size_t)tileM * K;
  const u16* Bg = B + (size_t)tileN * K;
  const int NT = K / 64;

  f32x4 acc[8][4] = {};
  short8 afr[8], bfr[8];

  // prologue: tile0 (all 4 halves) -> buf0; tile1 X halves -> buf1
  stage_half<64>(Ag, K, 0, As0, wave, lane, 0);
  stage_half<64>(Ag, K, 0, As0, wave, lane, 1);
  stage_half<32>(Bg, K, 0, Bs0, wave, lane, 0);
  stage_half<32>(Bg, K, 0, Bs0, wave, lane, 1);
  stage_half<64>(Ag, K, 64, As1, wave, lane, 0);
  stage_half<32>(Bg, K, 64, Bs1, wave, lane, 0);
  asm volatile("s_waitcnt vmcnt(4)" ::: "memory");   // tile0 landed
  BARX;

  for (int it = 0; it < NT / 2; ++it) {
    const int t = it * 2;
    const int k1 = (t + 1) * 64, k2 = (t + 2) * 64, k3 = (t + 3) * 64;
    const bool h2 = (t + 2) < NT;                    // h3 == h2 (NT even)
    // ---- tile t (buf0) ----
    // ph1: quadrant (0,0); stage A-Y(t+1)->buf1
    LDA_Q(As0, 0); LDB_Q(Bs0, 0);
    stage_half<64>(Ag, K, k1, As1, wave, lane, 1);
    BARX; MMA_Q(0, 0); BARX;
    // ph2: (0,1); stage B-Y(t+1)->buf1
    LDB_Q(Bs0, 1);
    stage_half<32>(Bg, K, k1, Bs1, wave, lane, 1);
    BARX; MMA_Q(0, 1); BARX;
    // ph3: (1,0); stage A-X(t+2)->buf0
    LDA_Q(As0, 1);
    if (h2) stage_half<64>(Ag, K, k2, As0, wave, lane, 0);
    BARX; MMA_Q(1, 0); BARX;
    // ph4: (1,1); stage B-X(t+2)->buf0; counted vmcnt -> tile t+1 landed
    if (h2) {
      stage_half<32>(Bg, K, k2, Bs0, wave, lane, 0);
      asm volatile("s_waitcnt vmcnt(4)" ::: "memory");
    } else {
      asm volatile("s_waitcnt vmcnt(0)" ::: "memory");
    }
    BARX; MMA_Q(1, 1); BARX;
    // ---- tile t+1 (buf1) ----
    // ph5: (0,0); stage A-Y(t+2)->buf0
    LDA_Q(As1, 0); LDB_Q(Bs1, 0);
    if (h2) stage_half<64>(Ag, K, k2, As0, wave, lane, 1);
    BARX; MMA_Q(0, 0); BARX;
    // ph6: (0,1); stage B-Y(t+2)->buf0
    LDB_Q(Bs1, 1);
    if (h2) stage_half<32>(Bg, K, k2, Bs0, wave, lane, 1);
    BARX; MMA_Q(0, 1); BARX;
    // ph7: (1,0); stage A-X(t+3)->buf1
    LDA_Q(As1, 1);
    if (h2) stage_half<64>(Ag, K, k3, As1, wave, lane, 0);
    BARX; MMA_Q(1, 0); BARX;
    // ph8: (1,1); stage B-X(t+3)->buf1; counted vmcnt -> tile t+2 landed
    if (h2) {
      stage_half<32>(Bg, K, k3, Bs1, wave, lane, 0);
      asm volatile("s_waitcnt vmcnt(4)" ::: "memory");
    } else {
      asm volatile("s_waitcnt vmcnt(0)" ::: "memory");
    }
    BARX; MMA_Q(1, 1); BARX;
  }

  // epilogue
  const int r0 = tileM + wr * 128 + ((lane >> 4) << 2);
  const int c0 = tileN + wc * 64 + (lane & 15);
  float theta = 0.f, inv2s2 = 0.f, bias = 0.f;
  if constexpr (EPI == 2) { inv2s2 = scF[1]; bias = biasp[0]; }
  if constexpr (EPI == 3) { theta = scF[0]; }
  (void)M;
#pragma unroll
  for (int m = 0; m < 8; ++m) {
#pragma unroll
    for (int j = 0; j < 4; ++j) {
      const int row = r0 + m * 16 + j;
      float rsr = 0.f, cr = 0.f;
      if constexpr (EPI == 3) rsr = rsqrtf(DVv[row]);
      if constexpr (EPI == 2) cr = rowv[row];
#pragma unroll
      for (int n = 0; n < 4; ++n) {
        const int col = c0 + n * 16;
        const size_t idx = (size_t)row * N + col;
        const float v = acc[m][n][j];
        if constexpr (EPI == 1) {
          outB[idx] = f2bf(v * scale);
        } else if constexpr (EPI == 2) {
          float dist = colv[col] + cr - 2.f * v + bias;
          outB[idx] = f2bf(__expf(-dist * inv2s2));
        } else {
          float gv = Gin[idx];
          outF[idx] = (1.f - theta) * gv + theta * rsr * rsqrtf(DVv[col]) * v;
        }
      }
    }
  }
}

// =================== 128x128 MFMA NT GEMM (skinny shapes) ====================
#define BM 128
#define BN 128
#define BK 64

template<int EPI>   // 0 = f32 store (atomicAdd when ksplit>1)
__global__ __launch_bounds__(256)
void gemm_nt(const u16* __restrict__ A, const u16* __restrict__ B,
             int M, int N, int K, int ksplit,
             float* __restrict__ outF)
{
  __shared__ __align__(16) u16 As[BM * BK];
  __shared__ __align__(16) u16 Bs[BN * BK];
  const int tid  = threadIdx.x;
  const int lane = tid & 63;
  const int wave = tid >> 6;
  const int wr = wave >> 1, wc = wave & 1;
  const int tileM = blockIdx.y * BM;
  const int tileN = blockIdx.x * BN;
  const int kper = K / ksplit;
  const int kbeg = blockIdx.z * kper;
  const int kend = kbeg + kper;

  const int srow = wave * 8 + (lane >> 3);
  const int scol = (lane & 7) * 8;

  f32x4 acc[4][4] = {};

  const u16* Arow = A + (size_t)tileM * K;
  const u16* Brow = B + (size_t)tileN * K;

  for (int kt = kbeg; kt < kend; kt += BK) {
    __syncthreads();
#pragma unroll
    for (int r = 0; r < 4; ++r) {
      int row = r * 32 + srow;
      gload_lds16(Arow + (size_t)row * K + kt + scol, &As[row * BK + scol]);
      gload_lds16(Brow + (size_t)row * K + kt + scol, &Bs[row * BK + scol]);
    }
    __syncthreads();
#pragma unroll
    for (int ks = 0; ks < 2; ++ks) {
      short8 af[4], bfq[4];
#pragma unroll
      for (int m = 0; m < 4; ++m)
        af[m] = *(const short8*)&As[(wr * 64 + m * 16 + (lane & 15)) * BK + ks * 32 + (lane >> 4) * 8];
#pragma unroll
      for (int n = 0; n < 4; ++n)
        bfq[n] = *(const short8*)&Bs[(wc * 64 + n * 16 + (lane & 15)) * BK + ks * 32 + (lane >> 4) * 8];
#pragma unroll
      for (int m = 0; m < 4; ++m)
#pragma unroll
        for (int n = 0; n < 4; ++n)
          acc[m][n] = __builtin_amdgcn_mfma_f32_16x16x32_bf16(af[m], bfq[n], acc[m][n], 0, 0, 0);
    }
  }

  const int r0 = tileM + wr * 64 + ((lane >> 4) << 2);
  const int c0 = tileN + wc * 64 + (lane & 15);
#pragma unroll
  for (int m = 0; m < 4; ++m) {
#pragma unroll
    for (int j = 0; j < 4; ++j) {
      const int row = r0 + m * 16 + j;
#pragma unroll
      for (int n = 0; n < 4; ++n) {
        const int col = c0 + n * 16;
        const size_t idx = (size_t)row * N + col;
        const float v = acc[m][n][j];
        if (ksplit == 1) outF[idx] = v; else atomicAdd(&outF[idx], v);
      }
    }
  }
}

// ---------------- utility kernels ----------------

__global__ void k_scalars(const int* num, const int* sigma, float* scF) {
  if (threadIdx.x == 0 && blockIdx.x == 0) {
    float n = (float)num[0];
    scF[0] = 1.f - (1.f - 0.01f) * (cosf(3.14159265358979f * (n - 1.f) / 10.f) + 1.f) * 0.5f;
    float s = (float)sigma[0];
    scF[1] = 1.f / (2.f * s * s);
  }
}

__global__ void k_deg(const float* __restrict__ adj, float* __restrict__ deg) {
  int e = blockIdx.x * 256 + threadIdx.x;
  int v0 = blockIdx.y * 128;
  float s = 0.f;
  for (int v = v0; v < v0 + 128; ++v) s += adj[(size_t)v * E_N + e];
  atomicAdd(&deg[e], s);
}

__global__ void k_convf(const float* __restrict__ in, u16* __restrict__ out, int n4) {
  int i = blockIdx.x * 256 + threadIdx.x;
  if (i >= n4) return;
  float4 v = ((const float4*)in)[i];
  ushort4 o; o.x = f2bf(v.x); o.y = f2bf(v.y); o.z = f2bf(v.z); o.w = f2bf(v.w);
  ((ushort4*)out)[i] = o;
}

__global__ void k_convW(const float* __restrict__ Wl, const float* __restrict__ Wv,
                        u16* __restrict__ WT) {
  int id = blockIdx.x * 256 + threadIdx.x;
  int n = id >> 9, k = id & 511;
  float v = (n < 256) ? Wl[(size_t)k * 256 + n] : Wv[(size_t)k * 256 + (n - 256)];
  WT[id] = f2bf(v);
}

__global__ void k_adjT(const float* __restrict__ adj, u16* __restrict__ adjT) {
  __shared__ float t[32][33];
  int e0 = blockIdx.x * 32, v0 = blockIdx.y * 32;
  int tx = threadIdx.x & 31, ty = threadIdx.x >> 5;
  for (int i = ty; i < 32; i += 8)
    t[i][tx] = adj[(size_t)(v0 + i) * E_N + e0 + tx];
  __syncthreads();
  for (int i = ty; i < 32; i += 8)
    adjT[(size_t)(e0 + i) * V_N + v0 + tx] = f2bf(t[tx][i]);
}

__global__ void k_splitfw(const float* __restrict__ fw, u16* __restrict__ fwlinT,
                          u16* __restrict__ fvb, u16* __restrict__ fvT) {
  __shared__ float t[32][33];
  int h0 = blockIdx.x * 32, v0 = blockIdx.y * 32;
  int tx = threadIdx.x & 31, ty = threadIdx.x >> 5;
  for (int i = ty; i < 32; i += 8) {
    float val = fw[(size_t)(v0 + i) * 512 + h0 + tx];
    t[i][tx] = val;
    if (h0 >= 256) fvb[(size_t)(v0 + i) * 256 + (h0 - 256) + tx] = f2bf(val);
  }
  __syncthreads();
  u16* oT = (h0 < 256) ? fwlinT : fvT;
  int hb = (h0 < 256) ? h0 : h0 - 256;
  for (int i = ty; i < 32; i += 8)
    oT[(size_t)(hb + i) * V_N + v0 + tx] = f2bf(t[tx][i]);
}

__global__ void k_ln(const float* __restrict__ X, const float* __restrict__ divv,
                     const float* __restrict__ g, const float* __restrict__ b,
                     const float* __restrict__ w, u16* __restrict__ outB,
                     float* __restrict__ outA, int mulw)
{
  __shared__ float sm[8];
  int row = blockIdx.x, tid = threadIdx.x, lane = tid & 63, wave = tid >> 6;
  float x = X[(size_t)row * 256 + tid];
  if (divv) x /= divv[row];
  float s1 = x, s2 = x * x;
#pragma unroll
  for (int o = 32; o > 0; o >>= 1) { s1 += __shfl_down(s1, o); s2 += __shfl_down(s2, o); }
  if (lane == 0) { sm[wave] = s1; sm[4 + wave] = s2; }
  __syncthreads();
  float sx  = sm[0] + sm[1] + sm[2] + sm[3];
  float sx2 = sm[4] + sm[5] + sm[6] + sm[7];
  float mu  = sx * (1.f / 256.f);
  float var = sx2 * (1.f / 256.f) - mu * mu;
  float rs  = rsqrtf(var + 1e-5f);
  float xln = (x - mu) * rs * g[tid] + b[tid];
  outB[(size_t)row * 256 + tid] = f2bf(mulw ? xln * w[tid] : xln);
  float t = w[tid] * xln * xln;
  __syncthreads();
#pragma unroll
  for (int o = 32; o > 0; o >>= 1) t += __shfl_down(t, o);
  if (lane == 0) sm[wave] = t;
  __syncthreads();
  if (tid == 0) outA[row] = sm[0] + sm[1] + sm[2] + sm[3];
}

__global__ void k_softmax(u16* __restrict__ S) {
  __shared__ float sm[8];
  size_t base = (size_t)blockIdx.x * 4096;
  int tid = threadIdx.x, lane = tid & 63, wave = tid >> 6;
  short8* p = (short8*)(S + base);
  short8 r0 = p[2 * tid], r1 = p[2 * tid + 1];
  float v[16];
#pragma unroll
  for (int i = 0; i < 8; ++i) { v[i] = bf2f((u16)r0[i]); v[8 + i] = bf2f((u16)r1[i]); }
  float mx = v[0];
#pragma unroll
  for (int i = 1; i < 16; ++i) mx = fmaxf(mx, v[i]);
#pragma unroll
  for (int o = 32; o > 0; o >>= 1) mx = fmaxf(mx, __shfl_down(mx, o));
  if (lane == 0) sm[wave] = mx;
  __syncthreads();
  mx = fmaxf(fmaxf(sm[0], sm[1]), fmaxf(sm[2], sm[3]));
  float se = 0.f;
#pragma unroll
  for (int i = 0; i < 16; ++i) { v[i] = __expf(v[i] - mx); se += v[i]; }
  __syncthreads();
#pragma unroll
  for (int o = 32; o > 0; o >>= 1) se += __shfl_down(se, o);
  if (lane == 0) sm[4 + wave] = se;
  __syncthreads();
  se = sm[4] + sm[5] + sm[6] + sm[7];
  float inv = 1.f / se;
#pragma unroll
  for (int i = 0; i < 8; ++i) { r0[i] = (short)f2bf(v[i] * inv); r1[i] = (short)f2bf(v[8 + i] * inv); }
  p[2 * tid] = r0; p[2 * tid + 1] = r1;
}

__global__ void k_rowsum(const u16* __restrict__ Hm, float* __restrict__ DV) {
  __shared__ float sm[4];
  int row = blockIdx.x, tid = threadIdx.x, lane = tid & 63, wave = tid >> 6;
  const short8* p = (const short8*)(Hm + (size_t)row * 2048);
  short8 r = p[tid];
  float s = 0.f;
#pragma unroll
  for (int i = 0; i < 8; ++i) s += bf2f((u16)r[i]);
#pragma unroll
  for (int o = 32; o > 0; o >>= 1) s += __shfl_down(s, o);
  if (lane == 0) sm[wave] = s;
  __syncthreads();
  if (tid == 0) DV[row] = sm[0] + sm[1] + sm[2] + sm[3];
}

__global__ void k_colsum(const u16* __restrict__ Hm, float* __restrict__ DE) {
  int e = blockIdx.x * 256 + threadIdx.x;
  int v0 = blockIdx.y * 128;
  float s = 0.f;
  for (int v = v0; v < v0 + 128; ++v) s += bf2f(Hm[(size_t)v * 2048 + e]);
  atomicAdd(&DE[e], s);
}

__global__ void k_makeHd(u16* __restrict__ Hm, const float* __restrict__ DE) {
  int id = blockIdx.x * 256 + threadIdx.x;
  int c = id & 255, row = id >> 8;
  short8* p = (short8*)(Hm + (size_t)row * 2048);
  short8 r = p[c];
  const float4* dp = (const float4*)(DE + c * 8);
  float4 d0 = dp[0], d1 = dp[1];
  float sc[8] = { rsqrtf(d0.x), rsqrtf(d0.y), rsqrtf(d0.z), rsqrtf(d0.w),
                  rsqrtf(d1.x), rsqrtf(d1.y), rsqrtf(d1.z), rsqrtf(d1.w) };
#pragma unroll
  for (int i = 0; i < 8; ++i) r[i] = (short)f2bf(bf2f((u16)r[i]) * sc[i]);
  p[c] = r;
}

// ---------------- host ----------------

extern "C" void kernel_launch(void* const* d_in, const int* in_sizes, int n_in,
                              void* d_out, int out_size, void* d_ws, size_t ws_size,
                              hipStream_t stream)
{
  const float* adj   = (const float*)d_in[0];
  const float* G     = (const float*)d_in[1];
  const float* feats = (const float*)d_in[2];
  const float* Wl    = (const float*)d_in[3];
  const float* Wv    = (const float*)d_in[4];
  const float* wo_w  = (const float*)d_in[5];
  const float* wo_b  = (const float*)d_in[6];
  const float* g1    = (const float*)d_in[7];
  const float* b1    = (const float*)d_in[8];
  const float* g2    = (const float*)d_in[9];
  const float* b2    = (const float*)d_in[10];
  const int*   num   = (const int*)d_in[11];
  const int*   sigma = (const int*)d_in[12];
  float* out = (float*)d_out;

  // opt-in to 128 KiB dynamic LDS for the big-tile kernel
  hipFuncSetAttribute((const void*)gemm_nt_big<1>, hipFuncAttributeMaxDynamicSharedMemorySize, 131072);
  hipFuncSetAttribute((const void*)gemm_nt_big<2>, hipFuncAttributeMaxDynamicSharedMemorySize, 131072);
  hipFuncSetAttribute((const void*)gemm_nt_big<3>, hipFuncAttributeMaxDynamicSharedMemorySize, 131072);

  char* w = (char*)d_ws;
  auto take = [&](size_t b) { void* p = (void*)w; w += (b + 255) & ~(size_t)255; return p; };
  float* scF   = (float*)take(256);
  float* deg   = (float*)take(E_N * 4);
  float* DV    = (float*)take(V_N * 4);
  float* DE    = (float*)take(E_N * 4);
  float* aE    = (float*)take(E_N * 4);
  float* cV    = (float*)take(V_N * 4);
  char* big0   = (char*)take((size_t)V_N * F_N * 2 + 512 * 512 * 2 + (size_t)E_N * V_N * 2);
  u16* featsb  = (u16*)big0;
  u16* WcatT   = (u16*)(big0 + (size_t)V_N * F_N * 2);
  u16* adjTb   = (u16*)(big0 + (size_t)V_N * F_N * 2 + 512 * 512 * 2);
  u16* Hb      = (u16*)big0;                         // alias, live after adjTb dead
  char* big1   = (char*)take((size_t)V_N * 512 * 4);
  float* fwcat = (float*)big1;
  float* d_mat = (float*)big1;                       // alias, live after fwcat dead
  u16* db      = (u16*)(big1 + (size_t)V_N * H_N * 4);
  u16* fwlinT  = (u16*)take((size_t)H_N * V_N * 2);
  u16* fvb     = (u16*)take((size_t)V_N * H_N * 2);
  u16* fvT     = (u16*)take((size_t)H_N * V_N * 2);
  float* s_raw = (float*)take((size_t)E_N * H_N * 4);
  u16* swb     = (u16*)take((size_t)E_N * H_N * 2);
  u16* scoresb = (u16*)take((size_t)V_N * V_N * 2);
  (void)in_sizes; (void)n_in; (void)out_size;
  if ((size_t)(w - (char*)d_ws) > ws_size) return;

  hipMemsetAsync(deg, 0, E_N * 4, stream);
  hipMemsetAsync(DE, 0, E_N * 4, stream);
  hipMemsetAsync(s_raw, 0, (size_t)E_N * H_N * 4, stream);

  k_scalars<<<1, 64, 0, stream>>>(num, sigma, scF);
  k_deg<<<dim3(E_N / 256, 32), 256, 0, stream>>>(adj, deg);
  k_convf<<<(V_N * F_N / 4) / 256, 256, 0, stream>>>(feats, featsb, V_N * F_N / 4);
  k_convW<<<(512 * 512) / 256, 256, 0, stream>>>(Wl, Wv, WcatT);
  k_adjT<<<dim3(E_N / 32, V_N / 32), 256, 0, stream>>>(adj, adjTb);

  // G1: fwcat = feats @ [W_lin|W_v]   (M=V, N=512, K=512)
  gemm_nt<0><<<dim3(512 / BN, V_N / BM), 256, 0, stream>>>(
      featsb, WcatT, V_N, 512, 512, 1, fwcat);
  k_splitfw<<<dim3(16, V_N / 32), 256, 0, stream>>>(fwcat, fwlinT, fvb, fvT);

  // G2: s_raw = adj.T @ fwlin   (M=E, N=H, K=V, split-K 8)
  gemm_nt<0><<<dim3(H_N / BN, E_N / BM, 8), 256, 0, stream>>>(
      adjTb, fwlinT, E_N, H_N, V_N, 8, s_raw);
  k_ln<<<E_N, 256, 0, stream>>>(s_raw, deg, g1, b1, wo_w, swb, aE, 1);

  // G3: scores = fv @ fv.T / 16   (bf16 out, 256^2 8-phase)
  gemm_nt_big<1><<<dim3(V_N / 256, V_N / 256), 512, 131072, stream>>>(
      fvb, fvb, V_N, V_N, H_N, 0.0625f,
      nullptr, scoresb, nullptr, nullptr, nullptr, nullptr, nullptr, nullptr);
  k_softmax<<<V_N, 256, 0, stream>>>(scoresb);

  hipMemsetAsync(d_mat, 0, (size_t)V_N * H_N * 4, stream);
  // G4: d = attn @ fv   (M=V, N=H, K=V, split-K 8)
  gemm_nt<0><<<dim3(H_N / BN, V_N / BM, 8), 256, 0, stream>>>(
      scoresb, fvT, V_N, H_N, V_N, 8, d_mat);
  k_ln<<<V_N, 256, 0, stream>>>(d_mat, nullptr, g2, b2, wo_w, db, cV, 0);

  // G5: Hb[v,e] = exp(-(a[e]+c[v]-2*(d.sw)+b)/(2*sigma^2))   (M=V, N=E, K=H)
  gemm_nt_big<2><<<dim3(E_N / 256, V_N / 256), 512, 131072, stream>>>(
      db, swb, V_N, E_N, H_N, 0.f,
      nullptr, Hb, cV, aE, scF, wo_b, nullptr, nullptr);

  k_rowsum<<<V_N, 256, 0, stream>>>(Hb, DV);
  k_colsum<<<dim3(E_N / 256, 32), 256, 0, stream>>>(Hb, DE);
  k_makeHd<<<V_N, 256, 0, stream>>>(Hb, DE);

  // G6: out = (1-theta)*G + theta*invDV_i*invDV_j*(Hd @ Hd.T)   (M=N=V, K=E)
  gemm_nt_big<3><<<dim3(V_N / 256, V_N / 256), 512, 131072, stream>>>(
      Hb, Hb, V_N, V_N, E_N, 0.f,
      out, nullptr, nullptr, nullptr, scF, nullptr, G, DV);
}

// Round 3
// 252.454 us; speedup vs baseline: 1.2124x; 1.0671x over previous
//
#include <hip/hip_runtime.h>
#include <hip/hip_bf16.h>
#include <math.h>

#define V_N 4096
#define E_N 2048
#define F_N 512
#define H_N 256

typedef unsigned short u16;
typedef unsigned char u8;
typedef unsigned long long ull;
typedef __attribute__((ext_vector_type(8))) short short8;
typedef __attribute__((ext_vector_type(4))) float f32x4;
typedef __attribute__((ext_vector_type(2))) unsigned long ul2;

__device__ __forceinline__ float bf2f(u16 u) {
  union { float f; unsigned int q; } x; x.q = ((unsigned int)u) << 16; return x.f;
}
__device__ __forceinline__ u16 f2bf(float f) {
  union { float f; unsigned int q; } x; x.f = f;
  unsigned int q = x.q + 0x7FFFu + ((x.q >> 16) & 1u);
  return (u16)(q >> 16);
}

__device__ __forceinline__ void gload16(const void* g, void* l) {
  __builtin_amdgcn_global_load_lds((const __attribute__((address_space(1))) void*)g,
                                   (__attribute__((address_space(3))) void*)l,
                                   16, 0, 0);
}

// pack 8 f32 -> 8 fp8 e4m3 (bytes k0..k0+7 ascending)
__device__ __forceinline__ ull pack8_fp8(const float* p) {
  int w0 = __builtin_amdgcn_cvt_pk_fp8_f32(p[0], p[1], 0, false);
  w0 = __builtin_amdgcn_cvt_pk_fp8_f32(p[2], p[3], w0, true);
  int w1 = __builtin_amdgcn_cvt_pk_fp8_f32(p[4], p[5], 0, false);
  w1 = __builtin_amdgcn_cvt_pk_fp8_f32(p[6], p[7], w1, true);
  return (ull)(unsigned int)w0 | ((ull)(unsigned int)w1 << 32);
}

// pi-permuted byte position of an 8-aligned k-chunk within a row:
// within each 64-col block, 16B chunk g holds [k=g*8..+7 | k=32+g*8..+7]
__device__ __forceinline__ int pi8(int k0) {
  return (k0 & ~63) + (((k0 >> 3) & 3) << 4) + (((k0 >> 5) & 1) << 3);
}

// =================== 256x256 8-phase fp8 NT GEMM (T1+T2+T3+T4+T5) ============
// C[m,n] = sum_k A[m,k]*B[n,k]. A:(M,K), B:(N,K) row-major fp8 e4m3 in
// pi-permuted column order. 512 threads = 8 waves (2Mx4N), wave tile 128x64,
// BK=64 (=64 bytes/row). LDS: 2 dbuf x (A 16KB + B 16KB) = 64 KiB.
// Swizzle: 16B chunk c of row R stored at c^(R&3) (both-sides involution).

#define BARX do { asm volatile("" ::: "memory"); __builtin_amdgcn_s_barrier(); \
                  asm volatile("" ::: "memory"); } while (0)

#define LDA_Q8(buf, mh_) do { \
  _Pragma("unroll") \
  for (int m_ = 0; m_ < 4; ++m_) { \
    int R_ = wr * 128 + (mh_) * 64 + m_ * 16 + (lane & 15); \
    int g_ = (lane >> 4) ^ (R_ & 3); \
    ul2 v_ = *(const ul2*)((buf) + R_ * 64 + g_ * 16); \
    a0[m_] = (long)v_[0]; a1[m_] = (long)v_[1]; \
  } \
} while (0)

#define LDB_Q8(buf, nh_) do { \
  _Pragma("unroll") \
  for (int n_ = 0; n_ < 2; ++n_) { \
    int R_ = wc * 64 + (nh_) * 32 + n_ * 16 + (lane & 15); \
    int g_ = (lane >> 4) ^ (R_ & 3); \
    ul2 v_ = *(const ul2*)((buf) + R_ * 64 + g_ * 16); \
    b0[(nh_) * 2 + n_] = (long)v_[0]; b1[(nh_) * 2 + n_] = (long)v_[1]; \
  } \
} while (0)

#define MMA_Q8(mh_, nh_) do { \
  __builtin_amdgcn_s_setprio(1); \
  _Pragma("unroll") \
  for (int m_ = 0; m_ < 4; ++m_) { \
    _Pragma("unroll") \
    for (int n_ = 0; n_ < 2; ++n_) { \
      acc[(mh_) * 4 + m_][(nh_) * 2 + n_] = __builtin_amdgcn_mfma_f32_16x16x32_fp8_fp8( \
          a0[m_], b0[(nh_) * 2 + n_], acc[(mh_) * 4 + m_][(nh_) * 2 + n_], 0, 0, 0); \
      acc[(mh_) * 4 + m_][(nh_) * 2 + n_] = __builtin_amdgcn_mfma_f32_16x16x32_fp8_fp8( \
          a1[m_], b1[(nh_) * 2 + n_], acc[(mh_) * 4 + m_][(nh_) * 2 + n_], 0, 0, 0); \
    } } \
  __builtin_amdgcn_s_setprio(0); \
} while (0)

// Stage one half-tile (128 rows x 64 B). BAND=64: halves {0-63,128-191}/{64-127,192-255};
// BAND=32: 32-row bands. One 16B global_load_lds per thread; dest linear, source XOR'd.
template<int BAND>
__device__ __forceinline__ void stage_half8(const u8* __restrict__ g, int K, int kt,
                                            u8* lds, int tid, int h) {
  int rl = tid >> 2;                               // 0..127
  int c  = tid & 3;
  int R  = (rl & (BAND - 1)) + (rl & ~(BAND - 1)) * 2 + h * BAND;
  gload16(g + (size_t)R * K + kt + ((c ^ (R & 3)) << 4), lds + R * 64 + (c << 4));
}

// EPI: 1 = bf16 store * scale
//      2 = H-matrix: bf16( exp(-(colv[col]+rowv[row]-2*acc+bias)*scF[1]) )
//      3 = blend:    f32( (1-scF[0])*G + scF[0]*rsqrt(DV[r])*rsqrt(DV[c])*acc )
template<int EPI>
__global__ __launch_bounds__(512, 2)
void gemm_nt_big8(const u8* __restrict__ A, const u8* __restrict__ B,
                  int N, int K, float scale,
                  float* __restrict__ outF, u16* __restrict__ outB,
                  const float* __restrict__ rowv, const float* __restrict__ colv,
                  const float* __restrict__ scF, const float* __restrict__ biasp,
                  const float* __restrict__ Gin, const float* __restrict__ DVv)
{
  extern __shared__ __align__(16) u8 lds8[];
  u8* As0 = lds8;
  u8* Bs0 = lds8 + 16384;
  u8* As1 = lds8 + 32768;
  u8* Bs1 = lds8 + 49152;

  const int tid = threadIdx.x, lane = tid & 63, wave = tid >> 6;
  const int wr = wave >> 2, wc = wave & 3;

  // XCD-aware bijective swizzle (nwg % 8 == 0 for all launches here)
  const int nwg = gridDim.x * gridDim.y;
  const int lin = blockIdx.y * gridDim.x + blockIdx.x;
  const int swz = (lin & 7) * (nwg >> 3) + (lin >> 3);
  const int bx = swz % gridDim.x, by = swz / gridDim.x;
  const int tileM = by * 256, tileN = bx * 256;

  const u8* Ag = A + (size_t)tileM * K;
  const u8* Bg = B + (size_t)tileN * K;
  const int NT = K / 64;

  f32x4 acc[8][4] = {};
  long a0[4], a1[4], b0[8], b1[8];

  // prologue: tile0 all halves -> buf0; tile1 X halves -> buf1
  stage_half8<64>(Ag, K, 0, As0, tid, 0);
  stage_half8<64>(Ag, K, 0, As0, tid, 1);
  stage_half8<32>(Bg, K, 0, Bs0, tid, 0);
  stage_half8<32>(Bg, K, 0, Bs0, tid, 1);
  stage_half8<64>(Ag, K, 64, As1, tid, 0);
  stage_half8<32>(Bg, K, 64, Bs1, tid, 0);
  asm volatile("s_waitcnt vmcnt(2)" ::: "memory");   // tile0 landed
  BARX;

  for (int it = 0; it < NT / 2; ++it) {
    const int t = it * 2;
    const int k1 = (t + 1) * 64, k2 = (t + 2) * 64, k3 = (t + 3) * 64;
    const bool h2 = (t + 2) < NT;                    // NT even -> h3 == h2
    // ---- tile t (buf0) ----
    LDA_Q8(As0, 0); LDB_Q8(Bs0, 0);
    stage_half8<64>(Ag, K, k1, As1, tid, 1);
    BARX; MMA_Q8(0, 0); BARX;

    LDB_Q8(Bs0, 1);
    stage_half8<32>(Bg, K, k1, Bs1, tid, 1);
    BARX; MMA_Q8(0, 1); BARX;

    LDA_Q8(As0, 1);
    if (h2) stage_half8<64>(Ag, K, k2, As0, tid, 0);
    BARX; MMA_Q8(1, 0); BARX;

    if (h2) {
      stage_half8<32>(Bg, K, k2, Bs0, tid, 0);
      asm volatile("s_waitcnt vmcnt(2)" ::: "memory");   // tile t+1 landed
    } else {
      asm volatile("s_waitcnt vmcnt(0)" ::: "memory");
    }
    BARX; MMA_Q8(1, 1); BARX;
    // ---- tile t+1 (buf1) ----
    LDA_Q8(As1, 0); LDB_Q8(Bs1, 0);
    if (h2) stage_half8<64>(Ag, K, k2, As0, tid, 1);
    BARX; MMA_Q8(0, 0); BARX;

    LDB_Q8(Bs1, 1);
    if (h2) stage_half8<32>(Bg, K, k2, Bs0, tid, 1);
    BARX; MMA_Q8(0, 1); BARX;

    LDA_Q8(As1, 1);
    if (h2) stage_half8<64>(Ag, K, k3, As1, tid, 0);
    BARX; MMA_Q8(1, 0); BARX;

    if (h2) {
      stage_half8<32>(Bg, K, k3, Bs1, tid, 0);
      asm volatile("s_waitcnt vmcnt(2)" ::: "memory");   // tile t+2 landed
    } else {
      asm volatile("s_waitcnt vmcnt(0)" ::: "memory");
    }
    BARX; MMA_Q8(1, 1); BARX;
  }

  // epilogue
  const int r0 = tileM + wr * 128 + ((lane >> 4) << 2);
  const int c0 = tileN + wc * 64 + (lane & 15);
  float theta = 0.f, inv2s2 = 0.f, bias = 0.f;
  if constexpr (EPI == 2) { inv2s2 = scF[1]; bias = biasp[0]; }
  if constexpr (EPI == 3) { theta = scF[0]; }
#pragma unroll
  for (int m = 0; m < 8; ++m) {
#pragma unroll
    for (int j = 0; j < 4; ++j) {
      const int row = r0 + m * 16 + j;
      float rsr = 0.f, cr = 0.f;
      if constexpr (EPI == 3) rsr = rsqrtf(DVv[row]);
      if constexpr (EPI == 2) cr = rowv[row];
#pragma unroll
      for (int n = 0; n < 4; ++n) {
        const int col = c0 + n * 16;
        const size_t idx = (size_t)row * N + col;
        const float v = acc[m][n][j];
        if constexpr (EPI == 1) {
          outB[idx] = f2bf(v * scale);
        } else if constexpr (EPI == 2) {
          float dist = colv[col] + cr - 2.f * v + bias;
          outB[idx] = f2bf(__expf(-dist * inv2s2));
        } else {
          float gv = Gin[idx];
          outF[idx] = (1.f - theta) * gv + theta * rsr * rsqrtf(DVv[col]) * v;
        }
      }
    }
  }
}

// =================== 128x128 bf16 MFMA NT GEMM (skinny shapes) ===============
#define BM 128
#define BN 128
#define BK 64

template<int EPI>   // 0 = f32 store (atomicAdd when ksplit>1)
__global__ __launch_bounds__(256)
void gemm_nt(const u16* __restrict__ A, const u16* __restrict__ B,
             int M, int N, int K, int ksplit,
             float* __restrict__ outF)
{
  __shared__ __align__(16) u16 As[BM * BK];
  __shared__ __align__(16) u16 Bs[BN * BK];
  const int tid  = threadIdx.x;
  const int lane = tid & 63;
  const int wave = tid >> 6;
  const int wr = wave >> 1, wc = wave & 1;
  const int tileM = blockIdx.y * BM;
  const int tileN = blockIdx.x * BN;
  const int kper = K / ksplit;
  const int kbeg = blockIdx.z * kper;
  const int kend = kbeg + kper;

  const int srow = wave * 8 + (lane >> 3);
  const int scol = (lane & 7) * 8;

  f32x4 acc[4][4] = {};

  const u16* Arow = A + (size_t)tileM * K;
  const u16* Brow = B + (size_t)tileN * K;

  for (int kt = kbeg; kt < kend; kt += BK) {
    __syncthreads();
#pragma unroll
    for (int r = 0; r < 4; ++r) {
      int row = r * 32 + srow;
      gload16(Arow + (size_t)row * K + kt + scol, &As[row * BK + scol]);
      gload16(Brow + (size_t)row * K + kt + scol, &Bs[row * BK + scol]);
    }
    __syncthreads();
#pragma unroll
    for (int ks = 0; ks < 2; ++ks) {
      short8 af[4], bfq[4];
#pragma unroll
      for (int m = 0; m < 4; ++m)
        af[m] = *(const short8*)&As[(wr * 64 + m * 16 + (lane & 15)) * BK + ks * 32 + (lane >> 4) * 8];
#pragma unroll
      for (int n = 0; n < 4; ++n)
        bfq[n] = *(const short8*)&Bs[(wc * 64 + n * 16 + (lane & 15)) * BK + ks * 32 + (lane >> 4) * 8];
#pragma unroll
      for (int m = 0; m < 4; ++m)
#pragma unroll
        for (int n = 0; n < 4; ++n)
          acc[m][n] = __builtin_amdgcn_mfma_f32_16x16x32_bf16(af[m], bfq[n], acc[m][n], 0, 0, 0);
    }
  }

  const int r0 = tileM + wr * 64 + ((lane >> 4) << 2);
  const int c0 = tileN + wc * 64 + (lane & 15);
#pragma unroll
  for (int m = 0; m < 4; ++m) {
#pragma unroll
    for (int j = 0; j < 4; ++j) {
      const int row = r0 + m * 16 + j;
#pragma unroll
      for (int n = 0; n < 4; ++n) {
        const int col = c0 + n * 16;
        const size_t idx = (size_t)row * N + col;
        const float v = acc[m][n][j];
        if (ksplit == 1) outF[idx] = v; else atomicAdd(&outF[idx], v);
      }
    }
  }
}

// ---------------- utility kernels ----------------

__global__ void k_scalars(const int* num, const int* sigma, float* scF) {
  if (threadIdx.x == 0 && blockIdx.x == 0) {
    float n = (float)num[0];
    scF[0] = 1.f - (1.f - 0.01f) * (cosf(3.14159265358979f * (n - 1.f) / 10.f) + 1.f) * 0.5f;
    float s = (float)sigma[0];
    scF[1] = 1.f / (2.f * s * s);
  }
}

__global__ void k_convf(const float* __restrict__ in, u16* __restrict__ out, int n4) {
  int i = blockIdx.x * 256 + threadIdx.x;
  if (i >= n4) return;
  float4 v = ((const float4*)in)[i];
  ushort4 o; o.x = f2bf(v.x); o.y = f2bf(v.y); o.z = f2bf(v.z); o.w = f2bf(v.w);
  ((ushort4*)out)[i] = o;
}

__global__ void k_convW(const float* __restrict__ Wl, const float* __restrict__ Wv,
                        u16* __restrict__ WT) {
  int id = blockIdx.x * 256 + threadIdx.x;
  int n = id >> 9, k = id & 511;
  float v = (n < 256) ? Wl[(size_t)k * 256 + n] : Wv[(size_t)k * 256 + (n - 256)];
  WT[id] = f2bf(v);
}

// transpose adj -> bf16 adjT, and fused column-degree accumulation
__global__ void k_adjT(const float* __restrict__ adj, u16* __restrict__ adjT,
                       float* __restrict__ deg) {
  __shared__ float t[32][33];
  int e0 = blockIdx.x * 32, v0 = blockIdx.y * 32;
  int tx = threadIdx.x & 31, ty = threadIdx.x >> 5;
  for (int i = ty; i < 32; i += 8)
    t[i][tx] = adj[(size_t)(v0 + i) * E_N + e0 + tx];
  __syncthreads();
  for (int i = ty; i < 32; i += 8)
    adjT[(size_t)(e0 + i) * V_N + v0 + tx] = f2bf(t[tx][i]);
  if (ty == 0) {
    float s = 0.f;
#pragma unroll
    for (int i = 0; i < 32; ++i) s += t[i][tx];
    atomicAdd(&deg[e0 + tx], s);
  }
}

// fwcat (V,512) -> fwlinT (256,V) bf16 [cols 0..255], fvT (256,V) bf16 [cols 256..511]
__global__ void k_splitfw(const float* __restrict__ fw, u16* __restrict__ fwlinT,
                          u16* __restrict__ fvT) {
  __shared__ float t[32][33];
  int h0 = blockIdx.x * 32, v0 = blockIdx.y * 32;
  int tx = threadIdx.x & 31, ty = threadIdx.x >> 5;
  for (int i = ty; i < 32; i += 8)
    t[i][tx] = fw[(size_t)(v0 + i) * 512 + h0 + tx];
  __syncthreads();
  u16* oT = (h0 < 256) ? fwlinT : fvT;
  int hb = (h0 < 256) ? h0 : h0 - 256;
  for (int i = ty; i < 32; i += 8)
    oT[(size_t)(hb + i) * V_N + v0 + tx] = f2bf(t[tx][i]);
}

// fwcat cols 256..511 -> fv fp8-pi (V x 256, 32 u64/row)
__global__ void k_cvtfv8(const float* __restrict__ fw, ull* __restrict__ fvb8) {
  int id = blockIdx.x * 256 + threadIdx.x;     // V*32
  int row = id >> 5, s = id & 31, k0 = s * 8;
  const float* p = &fw[(size_t)row * 512 + 256 + k0];
  float f[8];
#pragma unroll
  for (int i = 0; i < 8; ++i) f[i] = p[i];
  fvb8[(size_t)row * 32 + (pi8(k0) >> 3)] = pack8_fp8(f);
}

// LayerNorm over rows of 256 -> fp8-pi output + outA[row] = sum_h w*xln^2
__global__ void k_ln8(const float* __restrict__ X, const float* __restrict__ divv,
                      const float* __restrict__ g, const float* __restrict__ b,
                      const float* __restrict__ w, ull* __restrict__ out8,
                      float* __restrict__ outA, int mulw)
{
  __shared__ float sm[8];
  __shared__ float xb[256];
  int row = blockIdx.x, tid = threadIdx.x, lane = tid & 63, wave = tid >> 6;
  float x = X[(size_t)row * 256 + tid];
  if (divv) x /= divv[row];
  float s1 = x, s2 = x * x;
#pragma unroll
  for (int o = 32; o > 0; o >>= 1) { s1 += __shfl_down(s1, o); s2 += __shfl_down(s2, o); }
  if (lane == 0) { sm[wave] = s1; sm[4 + wave] = s2; }
  __syncthreads();
  float sx  = sm[0] + sm[1] + sm[2] + sm[3];
  float sx2 = sm[4] + sm[5] + sm[6] + sm[7];
  float mu  = sx * (1.f / 256.f);
  float var = sx2 * (1.f / 256.f) - mu * mu;
  float rs  = rsqrtf(var + 1e-5f);
  float xln = (x - mu) * rs * g[tid] + b[tid];
  xb[tid] = mulw ? xln * w[tid] : xln;
  float t = w[tid] * xln * xln;
  __syncthreads();
#pragma unroll
  for (int o = 32; o > 0; o >>= 1) t += __shfl_down(t, o);
  if (lane == 0) sm[wave] = t;
  __syncthreads();
  if (tid == 0) outA[row] = sm[0] + sm[1] + sm[2] + sm[3];
  if (tid < 32) {
    int k0 = tid * 8;
    out8[(size_t)row * 32 + (pi8(k0) >> 3)] = pack8_fp8(&xb[k0]);
  }
}

__global__ void k_softmax(u16* __restrict__ S) {
  __shared__ float sm[8];
  size_t base = (size_t)blockIdx.x * 4096;
  int tid = threadIdx.x, lane = tid & 63, wave = tid >> 6;
  short8* p = (short8*)(S + base);
  short8 r0 = p[2 * tid], r1 = p[2 * tid + 1];
  float v[16];
#pragma unroll
  for (int i = 0; i < 8; ++i) { v[i] = bf2f((u16)r0[i]); v[8 + i] = bf2f((u16)r1[i]); }
  float mx = v[0];
#pragma unroll
  for (int i = 1; i < 16; ++i) mx = fmaxf(mx, v[i]);
#pragma unroll
  for (int o = 32; o > 0; o >>= 1) mx = fmaxf(mx, __shfl_down(mx, o));
  if (lane == 0) sm[wave] = mx;
  __syncthreads();
  mx = fmaxf(fmaxf(sm[0], sm[1]), fmaxf(sm[2], sm[3]));
  float se = 0.f;
#pragma unroll
  for (int i = 0; i < 16; ++i) { v[i] = __expf(v[i] - mx); se += v[i]; }
  __syncthreads();
#pragma unroll
  for (int o = 32; o > 0; o >>= 1) se += __shfl_down(se, o);
  if (lane == 0) sm[4 + wave] = se;
  __syncthreads();
  se = sm[4] + sm[5] + sm[6] + sm[7];
  float inv = 1.f / se;
#pragma unroll
  for (int i = 0; i < 8; ++i) { r0[i] = (short)f2bf(v[i] * inv); r1[i] = (short)f2bf(v[8 + i] * inv); }
  p[2 * tid] = r0; p[2 * tid + 1] = r1;
}

__global__ void k_rowsum(const u16* __restrict__ Hm, float* __restrict__ DV) {
  __shared__ float sm[4];
  int row = blockIdx.x, tid = threadIdx.x, lane = tid & 63, wave = tid >> 6;
  const short8* p = (const short8*)(Hm + (size_t)row * 2048);
  short8 r = p[tid];
  float s = 0.f;
#pragma unroll
  for (int i = 0; i < 8; ++i) s += bf2f((u16)r[i]);
#pragma unroll
  for (int o = 32; o > 0; o >>= 1) s += __shfl_down(s, o);
  if (lane == 0) sm[wave] = s;
  __syncthreads();
  if (tid == 0) DV[row] = sm[0] + sm[1] + sm[2] + sm[3];
}

__global__ void k_colsum(const u16* __restrict__ Hm, float* __restrict__ DE) {
  int e = blockIdx.x * 256 + threadIdx.x;
  int v0 = blockIdx.y * 128;
  float s = 0.f;
  for (int v = v0; v < v0 + 128; ++v) s += bf2f(Hm[(size_t)v * 2048 + e]);
  atomicAdd(&DE[e], s);
}

// Hd8 = fp8-pi( Hb * rsqrt(DE[col]) )   (V x 2048)
__global__ void k_makeHd8(const u16* __restrict__ Hb, const float* __restrict__ DE,
                          ull* __restrict__ Hd8) {
  int id = blockIdx.x * 256 + threadIdx.x;     // V*256
  int row = id >> 8, s = id & 255, k0 = s * 8;
  const u16* hp = &Hb[(size_t)row * 2048 + k0];
  float f[8];
#pragma unroll
  for (int i = 0; i < 8; ++i) f[i] = bf2f(hp[i]) * rsqrtf(DE[k0 + i]);
  Hd8[(size_t)row * 256 + (pi8(k0) >> 3)] = pack8_fp8(f);
}

// ---------------- host ----------------

extern "C" void kernel_launch(void* const* d_in, const int* in_sizes, int n_in,
                              void* d_out, int out_size, void* d_ws, size_t ws_size,
                              hipStream_t stream)
{
  const float* adj   = (const float*)d_in[0];
  const float* G     = (const float*)d_in[1];
  const float* feats = (const float*)d_in[2];
  const float* Wl    = (const float*)d_in[3];
  const float* Wv    = (const float*)d_in[4];
  const float* wo_w  = (const float*)d_in[5];
  const float* wo_b  = (const float*)d_in[6];
  const float* g1    = (const float*)d_in[7];
  const float* b1    = (const float*)d_in[8];
  const float* g2    = (const float*)d_in[9];
  const float* b2    = (const float*)d_in[10];
  const int*   num   = (const int*)d_in[11];
  const int*   sigma = (const int*)d_in[12];
  float* out = (float*)d_out;

  hipFuncSetAttribute((const void*)gemm_nt_big8<1>, hipFuncAttributeMaxDynamicSharedMemorySize, 65536);
  hipFuncSetAttribute((const void*)gemm_nt_big8<2>, hipFuncAttributeMaxDynamicSharedMemorySize, 65536);
  hipFuncSetAttribute((const void*)gemm_nt_big8<3>, hipFuncAttributeMaxDynamicSharedMemorySize, 65536);

  char* w = (char*)d_ws;
  auto take = [&](size_t b) { void* p = (void*)w; w += (b + 255) & ~(size_t)255; return p; };
  float* scF   = (float*)take(256);
  float* deg   = (float*)take(E_N * 4);
  float* DV    = (float*)take(V_N * 4);
  float* DE    = (float*)take(E_N * 4);
  float* aE    = (float*)take(E_N * 4);
  float* cV    = (float*)take(V_N * 4);
  // big0: featsb + WcatT + adjTb; Hb aliases after adjTb is dead
  char* big0   = (char*)take((size_t)V_N * F_N * 2 + 512 * 512 * 2 + (size_t)E_N * V_N * 2);
  u16* featsb  = (u16*)big0;
  u16* WcatT   = (u16*)(big0 + (size_t)V_N * F_N * 2);
  u16* adjTb   = (u16*)(big0 + (size_t)V_N * F_N * 2 + 512 * 512 * 2);
  u16* Hb      = (u16*)big0;                         // V x E bf16 (16 MB)
  // big1 (8 MB): fwcat -> d_mat -> Hd8 (each dead before the next is written)
  char* big1   = (char*)take((size_t)V_N * 512 * 4);
  float* fwcat = (float*)big1;
  float* d_mat = (float*)big1;                       // V x H f32
  ull*   Hd8   = (ull*)big1;                         // V x E fp8-pi
  u16* fwlinT  = (u16*)take((size_t)H_N * V_N * 2);
  u16* fvT     = (u16*)take((size_t)H_N * V_N * 2);
  ull* fvb8    = (ull*)take((size_t)V_N * H_N);
  ull* db8     = (ull*)take((size_t)V_N * H_N);
  ull* swb8    = (ull*)take((size_t)E_N * H_N);
  float* s_raw = (float*)take((size_t)E_N * H_N * 4);
  u16* scoresb = (u16*)take((size_t)V_N * V_N * 2);
  (void)in_sizes; (void)n_in; (void)out_size;
  if ((size_t)(w - (char*)d_ws) > ws_size) return;

  hipMemsetAsync(deg, 0, E_N * 4, stream);
  hipMemsetAsync(DE, 0, E_N * 4, stream);
  hipMemsetAsync(s_raw, 0, (size_t)E_N * H_N * 4, stream);

  k_scalars<<<1, 64, 0, stream>>>(num, sigma, scF);
  k_convf<<<(V_N * F_N / 4) / 256, 256, 0, stream>>>(feats, featsb, V_N * F_N / 4);
  k_convW<<<(512 * 512) / 256, 256, 0, stream>>>(Wl, Wv, WcatT);
  k_adjT<<<dim3(E_N / 32, V_N / 32), 256, 0, stream>>>(adj, adjTb, deg);

  // G1: fwcat = feats @ [W_lin|W_v]   (M=V, N=512, K=512)
  gemm_nt<0><<<dim3(512 / BN, V_N / BM), 256, 0, stream>>>(
      featsb, WcatT, V_N, 512, 512, 1, fwcat);
  k_splitfw<<<dim3(16, V_N / 32), 256, 0, stream>>>(fwcat, fwlinT, fvT);
  k_cvtfv8<<<(V_N * 32) / 256, 256, 0, stream>>>(fwcat, fvb8);

  // G2: s_raw = adj.T @ fwlin   (M=E, N=H, K=V, split-K 8)
  gemm_nt<0><<<dim3(H_N / BN, E_N / BM, 8), 256, 0, stream>>>(
      adjTb, fwlinT, E_N, H_N, V_N, 8, s_raw);
  k_ln8<<<E_N, 256, 0, stream>>>(s_raw, deg, g1, b1, wo_w, swb8, aE, 1);

  // G3: scores = fv @ fv.T / 16   (fp8 in, bf16 out)
  gemm_nt_big8<1><<<dim3(V_N / 256, V_N / 256), 512, 65536, stream>>>(
      (const u8*)fvb8, (const u8*)fvb8, V_N, H_N, 0.0625f,
      nullptr, scoresb, nullptr, nullptr, nullptr, nullptr, nullptr, nullptr);
  k_softmax<<<V_N, 256, 0, stream>>>(scoresb);

  hipMemsetAsync(d_mat, 0, (size_t)V_N * H_N * 4, stream);
  // G4: d = attn @ fv   (M=V, N=H, K=V, split-K 8)
  gemm_nt<0><<<dim3(H_N / BN, V_N / BM, 8), 256, 0, stream>>>(
      scoresb, fvT, V_N, H_N, V_N, 8, d_mat);
  k_ln8<<<V_N, 256, 0, stream>>>(d_mat, nullptr, g2, b2, wo_w, db8, cV, 0);

  // G5: Hb[v,e] = exp(-(aE[e]+cV[v]-2*(d.sw)+b)/(2*sigma^2))   (M=V, N=E, K=H)
  gemm_nt_big8<2><<<dim3(E_N / 256, V_N / 256), 512, 65536, stream>>>(
      (const u8*)db8, (const u8*)swb8, E_N, H_N, 0.f,
      nullptr, Hb, cV, aE, scF, wo_b, nullptr, nullptr);

  k_rowsum<<<V_N, 256, 0, stream>>>(Hb, DV);
  k_colsum<<<dim3(E_N / 256, 32), 256, 0, stream>>>(Hb, DE);
  k_makeHd8<<<(V_N * 256) / 256, 256, 0, stream>>>(Hb, DE, Hd8);

  // G6: out = (1-theta)*G + theta*invDV_i*invDV_j*(Hd @ Hd.T)   (M=N=V, K=E)
  gemm_nt_big8<3><<<dim3(V_N / 256, V_N / 256), 512, 65536, stream>>>(
      (const u8*)Hd8, (const u8*)Hd8, V_N, E_N, 0.f,
      out, nullptr, nullptr, nullptr, scF, nullptr, G, DV);
}

// Round 4
// 251.037 us; speedup vs baseline: 1.2192x; 1.0056x over previous
//
#include <hip/hip_runtime.h>
#include <hip/hip_bf16.h>
#include <math.h>

#define V_N 4096
#define E_N 2048
#define F_N 512
#define H_N 256

typedef unsigned short u16;
typedef unsigned char u8;
typedef unsigned long long ull;
typedef __attribute__((ext_vector_type(8))) short short8;
typedef __attribute__((ext_vector_type(4))) float f32x4;
typedef __attribute__((ext_vector_type(2))) unsigned long ul2;

__device__ __forceinline__ float bf2f(u16 u) {
  union { float f; unsigned int q; } x; x.q = ((unsigned int)u) << 16; return x.f;
}
__device__ __forceinline__ u16 f2bf(float f) {
  union { float f; unsigned int q; } x; x.f = f;
  unsigned int q = x.q + 0x7FFFu + ((x.q >> 16) & 1u);
  return (u16)(q >> 16);
}

__device__ __forceinline__ void gload16(const void* g, void* l) {
  __builtin_amdgcn_global_load_lds((const __attribute__((address_space(1))) void*)g,
                                   (__attribute__((address_space(3))) void*)l,
                                   16, 0, 0);
}

// pack 8 f32 -> 8 fp8 e4m3 (bytes k0..k0+7 ascending)
__device__ __forceinline__ ull pack8_fp8(const float* p) {
  int w0 = __builtin_amdgcn_cvt_pk_fp8_f32(p[0], p[1], 0, false);
  w0 = __builtin_amdgcn_cvt_pk_fp8_f32(p[2], p[3], w0, true);
  int w1 = __builtin_amdgcn_cvt_pk_fp8_f32(p[4], p[5], 0, false);
  w1 = __builtin_amdgcn_cvt_pk_fp8_f32(p[6], p[7], w1, true);
  return (ull)(unsigned int)w0 | ((ull)(unsigned int)w1 << 32);
}

// pi-permuted byte position of an 8-aligned k-chunk within a row:
// within each 64-col block, 16B chunk g holds [k=g*8..+7 | k=32+g*8..+7]
__device__ __forceinline__ int pi8(int k0) {
  return (k0 & ~63) + (((k0 >> 3) & 3) << 4) + (((k0 >> 5) & 1) << 3);
}

// =================== 256x256 8-phase fp8 NT GEMM (T1+T2+T3+T4+T5) ============
// C[m,n] = sum_k A[m,k]*B[n,k]. A:(M,K), B:(N,K) row-major fp8 e4m3 in
// pi-permuted column order. 512 threads = 8 waves (2Mx4N), wave tile 128x64,
// BK=64 (=64 bytes/row). LDS: 2 dbuf x (A 16KB + B 16KB) = 64 KiB.
// Pair-row layout: chunk g of row R lives at (R>>1)*128 + ((g*2+(R&1))^((R>>1)&7))*16.
// A 16-lane b128 read phase hits each 16B slot-group exactly 2x (free).
// global_load_lds dest stays linear-in-lane; source address carries the inverse.

#define BARX do { asm volatile("" ::: "memory"); __builtin_amdgcn_s_barrier(); \
                  asm volatile("" ::: "memory"); } while (0)

#define LDA_Q8(buf, mh_) do { \
  _Pragma("unroll") \
  for (int m_ = 0; m_ < 4; ++m_) { \
    int R_ = wr * 128 + (mh_) * 64 + m_ * 16 + (lane & 15); \
    int q_ = R_ >> 1; \
    int s_ = (((lane >> 4) << 1) | (R_ & 1)) ^ (q_ & 7); \
    ul2 v_ = *(const ul2*)((buf) + q_ * 128 + s_ * 16); \
    a0[m_] = (long)v_[0]; a1[m_] = (long)v_[1]; \
  } \
} while (0)

#define LDB_Q8(buf, nh_) do { \
  _Pragma("unroll") \
  for (int n_ = 0; n_ < 2; ++n_) { \
    int R_ = wc * 64 + (nh_) * 32 + n_ * 16 + (lane & 15); \
    int q_ = R_ >> 1; \
    int s_ = (((lane >> 4) << 1) | (R_ & 1)) ^ (q_ & 7); \
    ul2 v_ = *(const ul2*)((buf) + q_ * 128 + s_ * 16); \
    b0[(nh_) * 2 + n_] = (long)v_[0]; b1[(nh_) * 2 + n_] = (long)v_[1]; \
  } \
} while (0)

#define MMA_Q8(mh_, nh_) do { \
  __builtin_amdgcn_s_setprio(1); \
  _Pragma("unroll") \
  for (int m_ = 0; m_ < 4; ++m_) { \
    _Pragma("unroll") \
    for (int n_ = 0; n_ < 2; ++n_) { \
      acc[(mh_) * 4 + m_][(nh_) * 2 + n_] = __builtin_amdgcn_mfma_f32_16x16x32_fp8_fp8( \
          a0[m_], b0[(nh_) * 2 + n_], acc[(mh_) * 4 + m_][(nh_) * 2 + n_], 0, 0, 0); \
      acc[(mh_) * 4 + m_][(nh_) * 2 + n_] = __builtin_amdgcn_mfma_f32_16x16x32_fp8_fp8( \
          a1[m_], b1[(nh_) * 2 + n_], acc[(mh_) * 4 + m_][(nh_) * 2 + n_], 0, 0, 0); \
    } } \
  __builtin_amdgcn_s_setprio(0); \
} while (0)

// Stage one half-tile (128 rows x 64 B). BAND=64: halves {0-63,128-191}/{64-127,192-255};
// BAND=32: 32-row bands. One 16B global_load_lds per thread; dest linear-in-lane,
// source carries the inverse of the pair-row layout.
template<int BAND>
__device__ __forceinline__ void stage_half8(const u8* __restrict__ g, int K, int kt,
                                            u8* lds, int tid, int h) {
  const int rs = BAND * 64;                      // bytes per contiguous region
  int o = tid * 16;                              // 0..8176
  int dest = (o / rs) * 2 * rs + (o % rs) + h * rs;
  int q = dest >> 7;
  int s = ((dest >> 4) & 7) ^ (q & 7);
  int R = 2 * q + (s & 1);
  int gch = s >> 1;
  gload16(g + (size_t)R * K + kt + (gch << 4), lds + dest);
}

// EPI: 1 = bf16 store * scale
//      2 = H-matrix: bf16(exp(-(colv[col]+rowv[row]-2*acc+bias)*scF[1])) + fused
//          DVo[row] += rowsum, DEo[col] += colsum (atomics, pre-zeroed)
//      3 = blend:    f32( (1-scF[0])*G + scF[0]*rsqrt(DV[r])*rsqrt(DV[c])*acc )
template<int EPI>
__global__ __launch_bounds__(512, 2)
void gemm_nt_big8(const u8* __restrict__ A, const u8* __restrict__ B,
                  int N, int K, float scale,
                  float* __restrict__ outF, u16* __restrict__ outB,
                  const float* __restrict__ rowv, const float* __restrict__ colv,
                  const float* __restrict__ scF, const float* __restrict__ biasp,
                  const float* __restrict__ Gin, const float* __restrict__ DVv,
                  float* __restrict__ DVo, float* __restrict__ DEo)
{
  extern __shared__ __align__(16) u8 lds8[];
  u8* As0 = lds8;
  u8* Bs0 = lds8 + 16384;
  u8* As1 = lds8 + 32768;
  u8* Bs1 = lds8 + 49152;

  const int tid = threadIdx.x, lane = tid & 63, wave = tid >> 6;
  const int wr = wave >> 2, wc = wave & 3;

  // XCD-aware bijective swizzle (nwg % 8 == 0 for all launches here)
  const int nwg = gridDim.x * gridDim.y;
  const int lin = blockIdx.y * gridDim.x + blockIdx.x;
  const int swz = (lin & 7) * (nwg >> 3) + (lin >> 3);
  const int bx = swz % gridDim.x, by = swz / gridDim.x;
  const int tileM = by * 256, tileN = bx * 256;

  const u8* Ag = A + (size_t)tileM * K;
  const u8* Bg = B + (size_t)tileN * K;
  const int NT = K / 64;

  f32x4 acc[8][4] = {};
  long a0[4], a1[4], b0[8], b1[8];

  // prologue: tile0 all halves -> buf0; tile1 X halves -> buf1
  stage_half8<64>(Ag, K, 0, As0, tid, 0);
  stage_half8<64>(Ag, K, 0, As0, tid, 1);
  stage_half8<32>(Bg, K, 0, Bs0, tid, 0);
  stage_half8<32>(Bg, K, 0, Bs0, tid, 1);
  stage_half8<64>(Ag, K, 64, As1, tid, 0);
  stage_half8<32>(Bg, K, 64, Bs1, tid, 0);
  asm volatile("s_waitcnt vmcnt(2)" ::: "memory");   // tile0 landed
  BARX;

  for (int it = 0; it < NT / 2; ++it) {
    const int t = it * 2;
    const int k1 = (t + 1) * 64, k2 = (t + 2) * 64, k3 = (t + 3) * 64;
    const bool h2 = (t + 2) < NT;                    // NT even -> h3 == h2
    // ---- tile t (buf0) ----
    LDA_Q8(As0, 0); LDB_Q8(Bs0, 0);
    stage_half8<64>(Ag, K, k1, As1, tid, 1);
    BARX; MMA_Q8(0, 0); BARX;

    LDB_Q8(Bs0, 1);
    stage_half8<32>(Bg, K, k1, Bs1, tid, 1);
    BARX; MMA_Q8(0, 1); BARX;

    LDA_Q8(As0, 1);
    if (h2) stage_half8<64>(Ag, K, k2, As0, tid, 0);
    BARX; MMA_Q8(1, 0); BARX;

    if (h2) {
      stage_half8<32>(Bg, K, k2, Bs0, tid, 0);
      asm volatile("s_waitcnt vmcnt(2)" ::: "memory");   // tile t+1 landed
    } else {
      asm volatile("s_waitcnt vmcnt(0)" ::: "memory");
    }
    BARX; MMA_Q8(1, 1); BARX;
    // ---- tile t+1 (buf1) ----
    LDA_Q8(As1, 0); LDB_Q8(Bs1, 0);
    if (h2) stage_half8<64>(Ag, K, k2, As0, tid, 1);
    BARX; MMA_Q8(0, 0); BARX;

    LDB_Q8(Bs1, 1);
    if (h2) stage_half8<32>(Bg, K, k2, Bs0, tid, 1);
    BARX; MMA_Q8(0, 1); BARX;

    LDA_Q8(As1, 1);
    if (h2) stage_half8<64>(Ag, K, k3, As1, tid, 0);
    BARX; MMA_Q8(1, 0); BARX;

    if (h2) {
      stage_half8<32>(Bg, K, k3, Bs1, tid, 0);
      asm volatile("s_waitcnt vmcnt(2)" ::: "memory");   // tile t+2 landed
    } else {
      asm volatile("s_waitcnt vmcnt(0)" ::: "memory");
    }
    BARX; MMA_Q8(1, 1); BARX;
  }

  // epilogue
  const int r0 = tileM + wr * 128 + ((lane >> 4) << 2);
  const int c0 = tileN + wc * 64 + (lane & 15);

  if constexpr (EPI == 2) {
    const float inv2s2 = scF[1], bias = biasp[0];
    float csum[4] = {0.f, 0.f, 0.f, 0.f};
#pragma unroll
    for (int m = 0; m < 8; ++m) {
#pragma unroll
      for (int j = 0; j < 4; ++j) {
        const int row = r0 + m * 16 + j;
        const float cr = rowv[row];
        float rsum = 0.f;
#pragma unroll
        for (int n = 0; n < 4; ++n) {
          const int col = c0 + n * 16;
          float dist = colv[col] + cr - 2.f * acc[m][n][j] + bias;
          float hv = __expf(-dist * inv2s2);
          outB[(size_t)row * N + col] = f2bf(hv);
          rsum += hv; csum[n] += hv;
        }
        rsum += __shfl_xor(rsum, 1); rsum += __shfl_xor(rsum, 2);
        rsum += __shfl_xor(rsum, 4); rsum += __shfl_xor(rsum, 8);
        if ((lane & 15) == 0) atomicAdd(&DVo[row], rsum);
      }
    }
#pragma unroll
    for (int n = 0; n < 4; ++n) {
      float c = csum[n];
      c += __shfl_xor(c, 16); c += __shfl_xor(c, 32);
      if (lane < 16) atomicAdd(&DEo[c0 + n * 16], c);
    }
  } else {
    float theta = 0.f;
    if constexpr (EPI == 3) theta = scF[0];
#pragma unroll
    for (int m = 0; m < 8; ++m) {
#pragma unroll
      for (int j = 0; j < 4; ++j) {
        const int row = r0 + m * 16 + j;
        float rsr = 0.f;
        if constexpr (EPI == 3) rsr = rsqrtf(DVv[row]);
#pragma unroll
        for (int n = 0; n < 4; ++n) {
          const int col = c0 + n * 16;
          const size_t idx = (size_t)row * N + col;
          const float v = acc[m][n][j];
          if constexpr (EPI == 1) {
            outB[idx] = f2bf(v * scale);
          } else {
            float gv = Gin[idx];
            outF[idx] = (1.f - theta) * gv + theta * rsr * rsqrtf(DVv[col]) * v;
          }
        }
      }
    }
  }
}

// =================== 128x128 bf16 MFMA NT GEMM (skinny shapes) ===============
#define BM 128
#define BN 128
#define BK 64

template<int EPI>   // 0 = f32 store (atomicAdd when ksplit>1); 1 = bf16 store
__global__ __launch_bounds__(256)
void gemm_nt(const u16* __restrict__ A, const u16* __restrict__ B,
             int M, int N, int K, int ksplit,
             float* __restrict__ outF, u16* __restrict__ outB)
{
  __shared__ __align__(16) u16 As[BM * BK];
  __shared__ __align__(16) u16 Bs[BN * BK];
  const int tid  = threadIdx.x;
  const int lane = tid & 63;
  const int wave = tid >> 6;
  const int wr = wave >> 1, wc = wave & 1;
  const int tileM = blockIdx.y * BM;
  const int tileN = blockIdx.x * BN;
  const int kper = K / ksplit;
  const int kbeg = blockIdx.z * kper;
  const int kend = kbeg + kper;

  const int srow = wave * 8 + (lane >> 3);
  const int scol = (lane & 7) * 8;

  f32x4 acc[4][4] = {};

  const u16* Arow = A + (size_t)tileM * K;
  const u16* Brow = B + (size_t)tileN * K;

  for (int kt = kbeg; kt < kend; kt += BK) {
    __syncthreads();
#pragma unroll
    for (int r = 0; r < 4; ++r) {
      int row = r * 32 + srow;
      gload16(Arow + (size_t)row * K + kt + scol, &As[row * BK + scol]);
      gload16(Brow + (size_t)row * K + kt + scol, &Bs[row * BK + scol]);
    }
    __syncthreads();
#pragma unroll
    for (int ks = 0; ks < 2; ++ks) {
      short8 af[4], bfq[4];
#pragma unroll
      for (int m = 0; m < 4; ++m)
        af[m] = *(const short8*)&As[(wr * 64 + m * 16 + (lane & 15)) * BK + ks * 32 + (lane >> 4) * 8];
#pragma unroll
      for (int n = 0; n < 4; ++n)
        bfq[n] = *(const short8*)&Bs[(wc * 64 + n * 16 + (lane & 15)) * BK + ks * 32 + (lane >> 4) * 8];
#pragma unroll
      for (int m = 0; m < 4; ++m)
#pragma unroll
        for (int n = 0; n < 4; ++n)
          acc[m][n] = __builtin_amdgcn_mfma_f32_16x16x32_bf16(af[m], bfq[n], acc[m][n], 0, 0, 0);
    }
  }

  const int r0 = tileM + wr * 64 + ((lane >> 4) << 2);
  const int c0 = tileN + wc * 64 + (lane & 15);
#pragma unroll
  for (int m = 0; m < 4; ++m) {
#pragma unroll
    for (int j = 0; j < 4; ++j) {
      const int row = r0 + m * 16 + j;
#pragma unroll
      for (int n = 0; n < 4; ++n) {
        const int col = c0 + n * 16;
        const size_t idx = (size_t)row * N + col;
        const float v = acc[m][n][j];
        if constexpr (EPI == 0) {
          if (ksplit == 1) outF[idx] = v; else atomicAdd(&outF[idx], v);
        } else {
          outB[idx] = f2bf(v);
        }
      }
    }
  }
}

// ---------------- utility kernels ----------------

__global__ void k_scalars(const int* num, const int* sigma, float* scF) {
  if (threadIdx.x == 0 && blockIdx.x == 0) {
    float n = (float)num[0];
    scF[0] = 1.f - (1.f - 0.01f) * (cosf(3.14159265358979f * (n - 1.f) / 10.f) + 1.f) * 0.5f;
    float s = (float)sigma[0];
    scF[1] = 1.f / (2.f * s * s);
  }
}

__global__ void k_convf(const float* __restrict__ in, u16* __restrict__ out, int n4) {
  int i = blockIdx.x * 256 + threadIdx.x;
  if (i >= n4) return;
  float4 v = ((const float4*)in)[i];
  ushort4 o; o.x = f2bf(v.x); o.y = f2bf(v.y); o.z = f2bf(v.z); o.w = f2bf(v.w);
  ((ushort4*)out)[i] = o;
}

__global__ void k_convW(const float* __restrict__ Wl, const float* __restrict__ Wv,
                        u16* __restrict__ WT) {
  int id = blockIdx.x * 256 + threadIdx.x;
  int n = id >> 9, k = id & 511;
  float v = (n < 256) ? Wl[(size_t)k * 256 + n] : Wv[(size_t)k * 256 + (n - 256)];
  WT[id] = f2bf(v);
}

// transpose adj -> bf16 adjT, and fused column-degree accumulation
__global__ void k_adjT(const float* __restrict__ adj, u16* __restrict__ adjT,
                       float* __restrict__ deg) {
  __shared__ float t[32][33];
  int e0 = blockIdx.x * 32, v0 = blockIdx.y * 32;
  int tx = threadIdx.x & 31, ty = threadIdx.x >> 5;
  for (int i = ty; i < 32; i += 8)
    t[i][tx] = adj[(size_t)(v0 + i) * E_N + e0 + tx];
  __syncthreads();
  for (int i = ty; i < 32; i += 8)
    adjT[(size_t)(e0 + i) * V_N + v0 + tx] = f2bf(t[tx][i]);
  if (ty == 0) {
    float s = 0.f;
#pragma unroll
    for (int i = 0; i < 32; ++i) s += t[i][tx];
    atomicAdd(&deg[e0 + tx], s);
  }
}

// fwcatb (V,512) bf16 -> fwlinT (256,V) bf16 [cols 0..255], fvT (256,V) bf16 [cols 256..511]
__global__ void k_splitfw(const u16* __restrict__ fw, u16* __restrict__ fwlinT,
                          u16* __restrict__ fvT) {
  __shared__ u16 t[32][33];
  int h0 = blockIdx.x * 32, v0 = blockIdx.y * 32;
  int tx = threadIdx.x & 31, ty = threadIdx.x >> 5;
  for (int i = ty; i < 32; i += 8)
    t[i][tx] = fw[(size_t)(v0 + i) * 512 + h0 + tx];
  __syncthreads();
  u16* oT = (h0 < 256) ? fwlinT : fvT;
  int hb = (h0 < 256) ? h0 : h0 - 256;
  for (int i = ty; i < 32; i += 8)
    oT[(size_t)(hb + i) * V_N + v0 + tx] = t[tx][i];
}

// fwcatb cols 256..511 (bf16) -> fv fp8-pi (V x 256, 32 u64/row)
__global__ void k_cvtfv8(const u16* __restrict__ fw, ull* __restrict__ fvb8) {
  int id = blockIdx.x * 256 + threadIdx.x;     // V*32
  int row = id >> 5, s = id & 31, k0 = s * 8;
  const u16* p = &fw[(size_t)row * 512 + 256 + k0];
  float f[8];
#pragma unroll
  for (int i = 0; i < 8; ++i) f[i] = bf2f(p[i]);
  fvb8[(size_t)row * 32 + (pi8(k0) >> 3)] = pack8_fp8(f);
}

// LayerNorm over rows of 256 -> fp8-pi output + outA[row] = sum_h w*xln^2
__global__ void k_ln8(const float* __restrict__ X, const float* __restrict__ divv,
                      const float* __restrict__ g, const float* __restrict__ b,
                      const float* __restrict__ w, ull* __restrict__ out8,
                      float* __restrict__ outA, int mulw)
{
  __shared__ float sm[8];
  __shared__ float xb[256];
  int row = blockIdx.x, tid = threadIdx.x, lane = tid & 63, wave = tid >> 6;
  float x = X[(size_t)row * 256 + tid];
  if (divv) x /= divv[row];
  float s1 = x, s2 = x * x;
#pragma unroll
  for (int o = 32; o > 0; o >>= 1) { s1 += __shfl_down(s1, o); s2 += __shfl_down(s2, o); }
  if (lane == 0) { sm[wave] = s1; sm[4 + wave] = s2; }
  __syncthreads();
  float sx  = sm[0] + sm[1] + sm[2] + sm[3];
  float sx2 = sm[4] + sm[5] + sm[6] + sm[7];
  float mu  = sx * (1.f / 256.f);
  float var = sx2 * (1.f / 256.f) - mu * mu;
  float rs  = rsqrtf(var + 1e-5f);
  float xln = (x - mu) * rs * g[tid] + b[tid];
  xb[tid] = mulw ? xln * w[tid] : xln;
  float t = w[tid] * xln * xln;
  __syncthreads();
#pragma unroll
  for (int o = 32; o > 0; o >>= 1) t += __shfl_down(t, o);
  if (lane == 0) sm[wave] = t;
  __syncthreads();
  if (tid == 0) outA[row] = sm[0] + sm[1] + sm[2] + sm[3];
  if (tid < 32) {
    int k0 = tid * 8;
    out8[(size_t)row * 32 + (pi8(k0) >> 3)] = pack8_fp8(&xb[k0]);
  }
}

__global__ void k_softmax(u16* __restrict__ S) {
  __shared__ float sm[8];
  size_t base = (size_t)blockIdx.x * 4096;
  int tid = threadIdx.x, lane = tid & 63, wave = tid >> 6;
  short8* p = (short8*)(S + base);
  short8 r0 = p[2 * tid], r1 = p[2 * tid + 1];
  float v[16];
#pragma unroll
  for (int i = 0; i < 8; ++i) { v[i] = bf2f((u16)r0[i]); v[8 + i] = bf2f((u16)r1[i]); }
  float mx = v[0];
#pragma unroll
  for (int i = 1; i < 16; ++i) mx = fmaxf(mx, v[i]);
#pragma unroll
  for (int o = 32; o > 0; o >>= 1) mx = fmaxf(mx, __shfl_down(mx, o));
  if (lane == 0) sm[wave] = mx;
  __syncthreads();
  mx = fmaxf(fmaxf(sm[0], sm[1]), fmaxf(sm[2], sm[3]));
  float se = 0.f;
#pragma unroll
  for (int i = 0; i < 16; ++i) { v[i] = __expf(v[i] - mx); se += v[i]; }
  __syncthreads();
#pragma unroll
  for (int o = 32; o > 0; o >>= 1) se += __shfl_down(se, o);
  if (lane == 0) sm[4 + wave] = se;
  __syncthreads();
  se = sm[4] + sm[5] + sm[6] + sm[7];
  float inv = 1.f / se;
#pragma unroll
  for (int i = 0; i < 8; ++i) { r0[i] = (short)f2bf(v[i] * inv); r1[i] = (short)f2bf(v[8 + i] * inv); }
  p[2 * tid] = r0; p[2 * tid + 1] = r1;
}

// Hd8 = fp8-pi( Hb * rsqrt(DE[col]) )   (V x 2048)
__global__ void k_makeHd8(const u16* __restrict__ Hb, const float* __restrict__ DE,
                          ull* __restrict__ Hd8) {
  int id = blockIdx.x * 256 + threadIdx.x;     // V*256
  int row = id >> 8, s = id & 255, k0 = s * 8;
  const u16* hp = &Hb[(size_t)row * 2048 + k0];
  float f[8];
#pragma unroll
  for (int i = 0; i < 8; ++i) f[i] = bf2f(hp[i]) * rsqrtf(DE[k0 + i]);
  Hd8[(size_t)row * 256 + (pi8(k0) >> 3)] = pack8_fp8(f);
}

// ---------------- host ----------------

extern "C" void kernel_launch(void* const* d_in, const int* in_sizes, int n_in,
                              void* d_out, int out_size, void* d_ws, size_t ws_size,
                              hipStream_t stream)
{
  const float* adj   = (const float*)d_in[0];
  const float* G     = (const float*)d_in[1];
  const float* feats = (const float*)d_in[2];
  const float* Wl    = (const float*)d_in[3];
  const float* Wv    = (const float*)d_in[4];
  const float* wo_w  = (const float*)d_in[5];
  const float* wo_b  = (const float*)d_in[6];
  const float* g1    = (const float*)d_in[7];
  const float* b1    = (const float*)d_in[8];
  const float* g2    = (const float*)d_in[9];
  const float* b2    = (const float*)d_in[10];
  const int*   num   = (const int*)d_in[11];
  const int*   sigma = (const int*)d_in[12];
  float* out = (float*)d_out;

  hipFuncSetAttribute((const void*)gemm_nt_big8<1>, hipFuncAttributeMaxDynamicSharedMemorySize, 65536);
  hipFuncSetAttribute((const void*)gemm_nt_big8<2>, hipFuncAttributeMaxDynamicSharedMemorySize, 65536);
  hipFuncSetAttribute((const void*)gemm_nt_big8<3>, hipFuncAttributeMaxDynamicSharedMemorySize, 65536);

  char* w = (char*)d_ws;
  auto take = [&](size_t b) { void* p = (void*)w; w += (b + 255) & ~(size_t)255; return p; };
  float* scF   = (float*)take(256);
  float* deg   = (float*)take(E_N * 4);
  float* DV    = (float*)take(V_N * 4);
  float* DE    = (float*)take(E_N * 4);
  float* aE    = (float*)take(E_N * 4);
  float* cV    = (float*)take(V_N * 4);
  // big0: featsb + WcatT + adjTb; Hb aliases after adjTb is dead
  char* big0   = (char*)take((size_t)V_N * F_N * 2 + 512 * 512 * 2 + (size_t)E_N * V_N * 2);
  u16* featsb  = (u16*)big0;
  u16* WcatT   = (u16*)(big0 + (size_t)V_N * F_N * 2);
  u16* adjTb   = (u16*)(big0 + (size_t)V_N * F_N * 2 + 512 * 512 * 2);
  u16* Hb      = (u16*)big0;                         // V x E bf16 (16 MB)
  // big1 (8 MB): fwcatb -> d_mat -> Hd8 (each dead before the next is written)
  char* big1   = (char*)take((size_t)V_N * 512 * 4);
  u16*   fwcatb = (u16*)big1;                        // V x 512 bf16 (4 MB)
  float* d_mat  = (float*)big1;                      // V x H f32 (4 MB)
  ull*   Hd8    = (ull*)big1;                        // V x E fp8-pi (8 MB)
  u16* fwlinT  = (u16*)take((size_t)H_N * V_N * 2);
  u16* fvT     = (u16*)take((size_t)H_N * V_N * 2);
  ull* fvb8    = (ull*)take((size_t)V_N * H_N);
  ull* db8     = (ull*)take((size_t)V_N * H_N);
  ull* swb8    = (ull*)take((size_t)E_N * H_N);
  float* s_raw = (float*)take((size_t)E_N * H_N * 4);
  u16* scoresb = (u16*)take((size_t)V_N * V_N * 2);
  (void)in_sizes; (void)n_in; (void)out_size;
  if ((size_t)(w - (char*)d_ws) > ws_size) return;

  hipMemsetAsync(deg, 0, E_N * 4, stream);
  hipMemsetAsync(DV, 0, V_N * 4, stream);
  hipMemsetAsync(DE, 0, E_N * 4, stream);
  hipMemsetAsync(s_raw, 0, (size_t)E_N * H_N * 4, stream);

  k_scalars<<<1, 64, 0, stream>>>(num, sigma, scF);
  k_convf<<<(V_N * F_N / 4) / 256, 256, 0, stream>>>(feats, featsb, V_N * F_N / 4);
  k_convW<<<(512 * 512) / 256, 256, 0, stream>>>(Wl, Wv, WcatT);
  k_adjT<<<dim3(E_N / 32, V_N / 32), 256, 0, stream>>>(adj, adjTb, deg);

  // G1: fwcatb = bf16(feats @ [W_lin|W_v])   (M=V, N=512, K=512)
  gemm_nt<1><<<dim3(512 / BN, V_N / BM), 256, 0, stream>>>(
      featsb, WcatT, V_N, 512, 512, 1, nullptr, fwcatb);
  k_splitfw<<<dim3(16, V_N / 32), 256, 0, stream>>>(fwcatb, fwlinT, fvT);
  k_cvtfv8<<<(V_N * 32) / 256, 256, 0, stream>>>(fwcatb, fvb8);

  // G2: s_raw = adj.T @ fwlin   (M=E, N=H, K=V, split-K 8)
  gemm_nt<0><<<dim3(H_N / BN, E_N / BM, 8), 256, 0, stream>>>(
      adjTb, fwlinT, E_N, H_N, V_N, 8, s_raw, nullptr);
  k_ln8<<<E_N, 256, 0, stream>>>(s_raw, deg, g1, b1, wo_w, swb8, aE, 1);

  // G3: scores = fv @ fv.T / 16   (fp8 in, bf16 out)
  gemm_nt_big8<1><<<dim3(V_N / 256, V_N / 256), 512, 65536, stream>>>(
      (const u8*)fvb8, (const u8*)fvb8, V_N, H_N, 0.0625f,
      nullptr, scoresb, nullptr, nullptr, nullptr, nullptr, nullptr, nullptr,
      nullptr, nullptr);
  k_softmax<<<V_N, 256, 0, stream>>>(scoresb);

  hipMemsetAsync(d_mat, 0, (size_t)V_N * H_N * 4, stream);
  // G4: d = attn @ fv   (M=V, N=H, K=V, split-K 8)
  gemm_nt<0><<<dim3(H_N / BN, V_N / BM, 8), 256, 0, stream>>>(
      scoresb, fvT, V_N, H_N, V_N, 8, d_mat, nullptr);
  k_ln8<<<V_N, 256, 0, stream>>>(d_mat, nullptr, g2, b2, wo_w, db8, cV, 0);

  // G5: Hb[v,e] = exp(-(aE[e]+cV[v]-2*(d.sw)+b)/(2*sigma^2)) + fused DV/DE sums
  gemm_nt_big8<2><<<dim3(E_N / 256, V_N / 256), 512, 65536, stream>>>(
      (const u8*)db8, (const u8*)swb8, E_N, H_N, 0.f,
      nullptr, Hb, cV, aE, scF, wo_b, nullptr, nullptr,
      DV, DE);

  k_makeHd8<<<(V_N * 256) / 256, 256, 0, stream>>>(Hb, DE, Hd8);

  // G6: out = (1-theta)*G + theta*invDV_i*invDV_j*(Hd @ Hd.T)   (M=N=V, K=E)
  gemm_nt_big8<3><<<dim3(V_N / 256, V_N / 256), 512, 65536, stream>>>(
      (const u8*)Hd8, (const u8*)Hd8, V_N, E_N, 0.f,
      out, nullptr, nullptr, nullptr, scF, nullptr, G, DV,
      nullptr, nullptr);
}